// Round 1
// baseline (8736.693 us; speedup 1.0000x reference)
//
#include <hip/hip_runtime.h>

#define H 64
#define DEE 16

// Accumulate acc[0..63] += x_row @ W, where x_row is nk4*4 floats read as float4
// from r (per-lane address), and W is [nk4*4][64] row-major, wave-uniform -> s_load.
__device__ __forceinline__ void mlp_accum(const float4* __restrict__ r, int nk4,
                                          const float* __restrict__ w, float* acc)
{
#pragma unroll 1
    for (int k4 = 0; k4 < nk4; ++k4) {
        float4 xv = r[k4];
        const float* wr = w + k4 * 4 * H;
#pragma unroll
        for (int j = 0; j < H; ++j) acc[j] = fmaf(xv.x, wr[j], acc[j]);
#pragma unroll
        for (int j = 0; j < H; ++j) acc[j] = fmaf(xv.y, wr[H + j], acc[j]);
#pragma unroll
        for (int j = 0; j < H; ++j) acc[j] = fmaf(xv.z, wr[2 * H + j], acc[j]);
#pragma unroll
        for (int j = 0; j < H; ++j) acc[j] = fmaf(xv.w, wr[3 * H + j], acc[j]);
    }
}

// Message MLP per edge + scatter-add into agg[dst].
// m = relu(cat[h[dst], h[src], ea] @ W1 + b1) @ W2 + b2 ; agg[dst] += m
__global__ void edge_msg_kernel(const float* __restrict__ hin,
                                const int* __restrict__ esrc,
                                const int* __restrict__ edst,
                                const float* __restrict__ ea,
                                const float* __restrict__ W1,  // [144][64]
                                const float* __restrict__ b1,  // [64]
                                const float* __restrict__ W2,  // [64][64]
                                const float* __restrict__ b2,  // [64]
                                float* __restrict__ agg,
                                int E)
{
    int e = blockIdx.x * blockDim.x + threadIdx.x;
    if (e >= E) return;
    const int src = esrc[e];
    const int dst = edst[e];

    float acc[H];
#pragma unroll
    for (int j = 0; j < H; ++j) acc[j] = b1[j];

    mlp_accum((const float4*)(hin + (size_t)dst * H), 16, W1, acc);
    mlp_accum((const float4*)(hin + (size_t)src * H), 16, W1 + 64 * H, acc);
    mlp_accum((const float4*)(ea + (size_t)e * DEE), 4, W1 + 128 * H, acc);

#pragma unroll
    for (int j = 0; j < H; ++j) acc[j] = fmaxf(acc[j], 0.0f);

    float* aggrow = agg + (size_t)dst * H;
#pragma unroll 1
    for (int jt = 0; jt < 4; ++jt) {
        float out[16];
        const float* wt = W2 + jt * 16;
#pragma unroll
        for (int jj = 0; jj < 16; ++jj) out[jj] = b2[jt * 16 + jj];
#pragma unroll
        for (int k = 0; k < H; ++k) {
            const float xk = acc[k];
            const float* wr = wt + k * H;
#pragma unroll
            for (int jj = 0; jj < 16; ++jj) out[jj] = fmaf(xk, wr[jj], out[jj]);
        }
#pragma unroll
        for (int jj = 0; jj < 16; ++jj) atomicAdd(aggrow + jt * 16 + jj, out[jj]);
    }
}

// Update MLP per node: h' = relu(relu(cat[h, agg] @ uW1 + ub1) @ uW2 + ub2)
__global__ void node_update_kernel(const float* __restrict__ hin,
                                   const float* __restrict__ agg,
                                   const float* __restrict__ W1,  // [128][64]
                                   const float* __restrict__ b1,
                                   const float* __restrict__ W2,  // [64][64]
                                   const float* __restrict__ b2,
                                   float* __restrict__ hout,
                                   int N)
{
    int n = blockIdx.x * blockDim.x + threadIdx.x;
    if (n >= N) return;

    float acc[H];
#pragma unroll
    for (int j = 0; j < H; ++j) acc[j] = b1[j];

    mlp_accum((const float4*)(hin + (size_t)n * H), 16, W1, acc);
    mlp_accum((const float4*)(agg + (size_t)n * H), 16, W1 + 64 * H, acc);

#pragma unroll
    for (int j = 0; j < H; ++j) acc[j] = fmaxf(acc[j], 0.0f);

    float4* orow = (float4*)(hout + (size_t)n * H);
#pragma unroll 1
    for (int jt = 0; jt < 4; ++jt) {
        float out[16];
        const float* wt = W2 + jt * 16;
#pragma unroll
        for (int jj = 0; jj < 16; ++jj) out[jj] = b2[jt * 16 + jj];
#pragma unroll
        for (int k = 0; k < H; ++k) {
            const float xk = acc[k];
            const float* wr = wt + k * H;
#pragma unroll
            for (int jj = 0; jj < 16; ++jj) out[jj] = fmaf(xk, wr[jj], out[jj]);
        }
#pragma unroll
        for (int q = 0; q < 4; ++q) {
            float4 o;
            o.x = fmaxf(out[q * 4 + 0], 0.0f);
            o.y = fmaxf(out[q * 4 + 1], 0.0f);
            o.z = fmaxf(out[q * 4 + 2], 0.0f);
            o.w = fmaxf(out[q * 4 + 3], 0.0f);
            orow[jt * 4 + q] = o;
        }
    }
}

// One wave per node: coalesced atomic accumulation into per-graph pooled sums.
__global__ void pool_kernel(const float* __restrict__ h,
                            const int* __restrict__ batch,
                            float* __restrict__ pooled,
                            float* __restrict__ counts,
                            int N)
{
    int t = blockIdx.x * blockDim.x + threadIdx.x;
    int n = t >> 6;
    int lane = t & 63;
    if (n >= N) return;
    int g = batch[n];
    atomicAdd(&pooled[(size_t)g * H + lane], h[(size_t)n * H + lane]);
    if (lane == 0) atomicAdd(&counts[g], 1.0f);
}

// One 64-thread block per graph: mean, then relu(p@lin1+b1)@lin2+b2
__global__ void head_kernel(const float* __restrict__ pooled,
                            const float* __restrict__ counts,
                            const float* __restrict__ lin1w,  // [64][64]
                            const float* __restrict__ lin1b,  // [64]
                            const float* __restrict__ lin2w,  // [64]
                            const float* __restrict__ lin2b,  // [1]
                            float* __restrict__ out,
                            int G)
{
    int g = blockIdx.x;
    int j = threadIdx.x;
    __shared__ float p[H];
    float c = fmaxf(counts[g], 1.0f);
    p[j] = pooled[(size_t)g * H + j] / c;
    __syncthreads();

    float accj = lin1b[j];
#pragma unroll
    for (int k = 0; k < H; ++k) accj = fmaf(p[k], lin1w[k * H + j], accj);
    accj = fmaxf(accj, 0.0f) * lin2w[j];

#pragma unroll
    for (int off = 32; off >= 1; off >>= 1) accj += __shfl_down(accj, off);
    if (j == 0) out[g] = accj + lin2b[0];
}

extern "C" void kernel_launch(void* const* d_in, const int* in_sizes, int n_in,
                              void* d_out, int out_size, void* d_ws, size_t ws_size,
                              hipStream_t stream)
{
    const float* x      = (const float*)d_in[0];
    const int*   eidx   = (const int*)d_in[1];   // [2][E]: row0 = src, row1 = dst
    const float* ea     = (const float*)d_in[2];
    const int*   batch  = (const int*)d_in[3];
    const float* mW1    = (const float*)d_in[4];   // [L][144][64]
    const float* mb1    = (const float*)d_in[5];   // [L][64]
    const float* mW2    = (const float*)d_in[6];   // [L][64][64]
    const float* mb2    = (const float*)d_in[7];
    const float* uW1    = (const float*)d_in[8];   // [L][128][64]
    const float* ub1    = (const float*)d_in[9];
    const float* uW2    = (const float*)d_in[10];  // [L][64][64]
    const float* ub2    = (const float*)d_in[11];
    const float* lin1w  = (const float*)d_in[12];
    const float* lin1b  = (const float*)d_in[13];
    const float* lin2w  = (const float*)d_in[14];
    const float* lin2b  = (const float*)d_in[15];

    const int N = in_sizes[0] / H;
    const int E = in_sizes[1] / 2;
    const int G = out_size;

    float* hA     = (float*)d_ws;
    float* hB     = hA + (size_t)N * H;
    float* agg    = hB + (size_t)N * H;
    float* pooled = agg + (size_t)N * H;
    float* counts = pooled + (size_t)G * H;

    const int* esrc = eidx;
    const int* edst = eidx + E;

    const float* hin = x;
    float* houts[3] = {hA, hB, hA};

    for (int l = 0; l < 3; ++l) {
        hipMemsetAsync(agg, 0, (size_t)N * H * sizeof(float), stream);
        edge_msg_kernel<<<(E + 255) / 256, 256, 0, stream>>>(
            hin, esrc, edst, ea,
            mW1 + (size_t)l * 144 * H, mb1 + (size_t)l * H,
            mW2 + (size_t)l * H * H,   mb2 + (size_t)l * H,
            agg, E);
        node_update_kernel<<<(N + 255) / 256, 256, 0, stream>>>(
            hin, agg,
            uW1 + (size_t)l * 128 * H, ub1 + (size_t)l * H,
            uW2 + (size_t)l * H * H,   ub2 + (size_t)l * H,
            houts[l], N);
        hin = houts[l];
    }

    hipMemsetAsync(pooled, 0, ((size_t)G * H + G) * sizeof(float), stream);
    pool_kernel<<<((size_t)N * H + 255) / 256, 256, 0, stream>>>(hin, batch, pooled, counts, N);
    head_kernel<<<G, H, 0, stream>>>(pooled, counts, lin1w, lin1b, lin2w, lin2b,
                                     (float*)d_out, G);
}

// Round 2
// 1381.405 us; speedup vs baseline: 6.3245x; 6.3245x over previous
//
#include <hip/hip_runtime.h>

#define H 64

// ---------------- fused tiled edge-message GEMM ----------------
// 512 threads = 8 waves; wave w owns output cols [8w, 8w+8).
// M-tile 128 edges. A = cat[h[dst], h[src], ea] staged to LDS [128][PAD_E].
// Lane l computes rows {l, l+64} x 8 cols -> 16 fp32 accumulators.
// Weights fetched via wave-uniform scalar loads (amortized across 128 edges).
#define ME 128
#define PAD_E 148   // PAD/4 odd -> b128 reads hit the canonical conflict-free pattern
#define PAD_R 68    // 68/4 = 17 odd
#define O2_OFF 8704 // 128*68; O2 region disjoint from R1 region

__global__ __launch_bounds__(512, 2)
void edge_msg_kernel(const float* __restrict__ hin,
                     const int* __restrict__ esrc,
                     const int* __restrict__ edst,
                     const float* __restrict__ ea,
                     const float* __restrict__ W1, const float* __restrict__ b1,
                     const float* __restrict__ W2, const float* __restrict__ b2,
                     float* __restrict__ agg, int E)
{
    extern __shared__ float sm[];
    const int t = threadIdx.x;
    const int e0 = blockIdx.x * ME;

    // ---- stage A-tile: rows = edges, cols = [h_dst | h_src | ea] ----
    {
        const int k4 = t & 15, mp = t >> 4;   // 16 float4-chunks per 64-col part
#pragma unroll
        for (int p = 0; p < 4; ++p) {
            const int m = mp + 32 * p;
            const int d = edst[e0 + m];
            const int s = esrc[e0 + m];
            float4 vd = *(const float4*)&hin[(size_t)d * H + 4 * k4];
            float4 vs = *(const float4*)&hin[(size_t)s * H + 4 * k4];
            *(float4*)&sm[m * PAD_E + 4 * k4] = vd;
            *(float4*)&sm[m * PAD_E + 64 + 4 * k4] = vs;
        }
        const int m2 = t >> 2, q = t & 3;     // 4 float4-chunks of edge_attr
        float4 ve = *(const float4*)&ea[(size_t)(e0 + m2) * 16 + 4 * q];
        *(float4*)&sm[m2 * PAD_E + 128 + 4 * q] = ve;
    }
    __syncthreads();

    const int l = t & 63;
    const int wq = __builtin_amdgcn_readfirstlane(t >> 6);  // force scalar path

    // ---- GEMM1: [128 x 144] @ W1[144 x 64], cols 8wq..8wq+7 ----
    float acc0[8], acc1[8];
#pragma unroll
    for (int j = 0; j < 8; ++j) { float b = b1[wq * 8 + j]; acc0[j] = b; acc1[j] = b; }
    {
        const float* Bp = W1 + wq * 8;
#pragma unroll 2
        for (int k4 = 0; k4 < 36; ++k4) {
            float4 A0 = *(const float4*)&sm[l * PAD_E + 4 * k4];
            float4 A1 = *(const float4*)&sm[(l + 64) * PAD_E + 4 * k4];
            const float* a0 = (const float*)&A0;
            const float* a1 = (const float*)&A1;
            const float* bp = Bp + 4 * k4 * H;
#pragma unroll
            for (int kk = 0; kk < 4; ++kk)
#pragma unroll
                for (int j = 0; j < 8; ++j) {
                    const float w = bp[kk * H + j];
                    acc0[j] = fmaf(a0[kk], w, acc0[j]);
                    acc1[j] = fmaf(a1[kk], w, acc1[j]);
                }
        }
    }
    __syncthreads();  // all waves done reading A

    // ---- relu -> R1 in LDS [128][PAD_R] ----
    {
        float4 r;
        r.x = fmaxf(acc0[0], 0.f); r.y = fmaxf(acc0[1], 0.f);
        r.z = fmaxf(acc0[2], 0.f); r.w = fmaxf(acc0[3], 0.f);
        *(float4*)&sm[l * PAD_R + wq * 8] = r;
        r.x = fmaxf(acc0[4], 0.f); r.y = fmaxf(acc0[5], 0.f);
        r.z = fmaxf(acc0[6], 0.f); r.w = fmaxf(acc0[7], 0.f);
        *(float4*)&sm[l * PAD_R + wq * 8 + 4] = r;
        r.x = fmaxf(acc1[0], 0.f); r.y = fmaxf(acc1[1], 0.f);
        r.z = fmaxf(acc1[2], 0.f); r.w = fmaxf(acc1[3], 0.f);
        *(float4*)&sm[(l + 64) * PAD_R + wq * 8] = r;
        r.x = fmaxf(acc1[4], 0.f); r.y = fmaxf(acc1[5], 0.f);
        r.z = fmaxf(acc1[6], 0.f); r.w = fmaxf(acc1[7], 0.f);
        *(float4*)&sm[(l + 64) * PAD_R + wq * 8 + 4] = r;
    }
    __syncthreads();

    // ---- GEMM2: [128 x 64] @ W2[64 x 64] ----
    float c0[8], c1[8];
#pragma unroll
    for (int j = 0; j < 8; ++j) { float b = b2[wq * 8 + j]; c0[j] = b; c1[j] = b; }
    {
        const float* Bp = W2 + wq * 8;
#pragma unroll 2
        for (int k4 = 0; k4 < 16; ++k4) {
            float4 A0 = *(const float4*)&sm[l * PAD_R + 4 * k4];
            float4 A1 = *(const float4*)&sm[(l + 64) * PAD_R + 4 * k4];
            const float* a0 = (const float*)&A0;
            const float* a1 = (const float*)&A1;
            const float* bp = Bp + 4 * k4 * H;
#pragma unroll
            for (int kk = 0; kk < 4; ++kk)
#pragma unroll
                for (int j = 0; j < 8; ++j) {
                    const float w = bp[kk * H + j];
                    c0[j] = fmaf(a0[kk], w, c0[j]);
                    c1[j] = fmaf(a1[kk], w, c1[j]);
                }
        }
    }
    // O2 region is disjoint from R1 region -> no barrier needed before writing
    {
        float4 r;
        r.x = c0[0]; r.y = c0[1]; r.z = c0[2]; r.w = c0[3];
        *(float4*)&sm[O2_OFF + l * PAD_R + wq * 8] = r;
        r.x = c0[4]; r.y = c0[5]; r.z = c0[6]; r.w = c0[7];
        *(float4*)&sm[O2_OFF + l * PAD_R + wq * 8 + 4] = r;
        r.x = c1[0]; r.y = c1[1]; r.z = c1[2]; r.w = c1[3];
        *(float4*)&sm[O2_OFF + (l + 64) * PAD_R + wq * 8] = r;
        r.x = c1[4]; r.y = c1[5]; r.z = c1[6]; r.w = c1[7];
        *(float4*)&sm[O2_OFF + (l + 64) * PAD_R + wq * 8 + 4] = r;
    }
    __syncthreads();

    // ---- coalesced atomic scatter: wave = one edge row, lanes = 64 cols ----
#pragma unroll 1
    for (int p = 0; p < 16; ++p) {
        const int m = wq + 8 * p;
        const float v = sm[O2_OFF + m * PAD_R + l];
        const int d = edst[e0 + m];
        atomicAdd(&agg[(size_t)d * H + l], v);
    }
}

// ---------------- tiled node-update GEMM ----------------
// Same structure; A = cat[h[n], agg[n]] (K=128), rows are contiguous nodes.
#define PAD_N 140   // 140/4 = 35 odd; 128*140 = 17920 dwords >= R1+O2 (17408)

__global__ __launch_bounds__(512, 2)
void node_update_kernel(const float* __restrict__ hin,
                        const float* __restrict__ agg,
                        const float* __restrict__ W1, const float* __restrict__ b1,
                        const float* __restrict__ W2, const float* __restrict__ b2,
                        float* __restrict__ hout, int N)
{
    extern __shared__ float sm[];
    const int t = threadIdx.x;
    const int n0 = blockIdx.x * ME;

    {
        const int k4 = t & 15, mp = t >> 4;
#pragma unroll
        for (int p = 0; p < 4; ++p) {
            const int m = mp + 32 * p;
            const int n = n0 + m;
            float4 vh = make_float4(0.f, 0.f, 0.f, 0.f);
            float4 va = vh;
            if (n < N) {
                vh = *(const float4*)&hin[(size_t)n * H + 4 * k4];
                va = *(const float4*)&agg[(size_t)n * H + 4 * k4];
            }
            *(float4*)&sm[m * PAD_N + 4 * k4] = vh;
            *(float4*)&sm[m * PAD_N + 64 + 4 * k4] = va;
        }
    }
    __syncthreads();

    const int l = t & 63;
    const int wq = __builtin_amdgcn_readfirstlane(t >> 6);

    float acc0[8], acc1[8];
#pragma unroll
    for (int j = 0; j < 8; ++j) { float b = b1[wq * 8 + j]; acc0[j] = b; acc1[j] = b; }
    {
        const float* Bp = W1 + wq * 8;
#pragma unroll 2
        for (int k4 = 0; k4 < 32; ++k4) {
            float4 A0 = *(const float4*)&sm[l * PAD_N + 4 * k4];
            float4 A1 = *(const float4*)&sm[(l + 64) * PAD_N + 4 * k4];
            const float* a0 = (const float*)&A0;
            const float* a1 = (const float*)&A1;
            const float* bp = Bp + 4 * k4 * H;
#pragma unroll
            for (int kk = 0; kk < 4; ++kk)
#pragma unroll
                for (int j = 0; j < 8; ++j) {
                    const float w = bp[kk * H + j];
                    acc0[j] = fmaf(a0[kk], w, acc0[j]);
                    acc1[j] = fmaf(a1[kk], w, acc1[j]);
                }
        }
    }
    __syncthreads();
    {
        float4 r;
        r.x = fmaxf(acc0[0], 0.f); r.y = fmaxf(acc0[1], 0.f);
        r.z = fmaxf(acc0[2], 0.f); r.w = fmaxf(acc0[3], 0.f);
        *(float4*)&sm[l * PAD_R + wq * 8] = r;
        r.x = fmaxf(acc0[4], 0.f); r.y = fmaxf(acc0[5], 0.f);
        r.z = fmaxf(acc0[6], 0.f); r.w = fmaxf(acc0[7], 0.f);
        *(float4*)&sm[l * PAD_R + wq * 8 + 4] = r;
        r.x = fmaxf(acc1[0], 0.f); r.y = fmaxf(acc1[1], 0.f);
        r.z = fmaxf(acc1[2], 0.f); r.w = fmaxf(acc1[3], 0.f);
        *(float4*)&sm[(l + 64) * PAD_R + wq * 8] = r;
        r.x = fmaxf(acc1[4], 0.f); r.y = fmaxf(acc1[5], 0.f);
        r.z = fmaxf(acc1[6], 0.f); r.w = fmaxf(acc1[7], 0.f);
        *(float4*)&sm[(l + 64) * PAD_R + wq * 8 + 4] = r;
    }
    __syncthreads();

    float c0[8], c1[8];
#pragma unroll
    for (int j = 0; j < 8; ++j) { float b = b2[wq * 8 + j]; c0[j] = b; c1[j] = b; }
    {
        const float* Bp = W2 + wq * 8;
#pragma unroll 2
        for (int k4 = 0; k4 < 16; ++k4) {
            float4 A0 = *(const float4*)&sm[l * PAD_R + 4 * k4];
            float4 A1 = *(const float4*)&sm[(l + 64) * PAD_R + 4 * k4];
            const float* a0 = (const float*)&A0;
            const float* a1 = (const float*)&A1;
            const float* bp = Bp + 4 * k4 * H;
#pragma unroll
            for (int kk = 0; kk < 4; ++kk)
#pragma unroll
                for (int j = 0; j < 8; ++j) {
                    const float w = bp[kk * H + j];
                    c0[j] = fmaf(a0[kk], w, c0[j]);
                    c1[j] = fmaf(a1[kk], w, c1[j]);
                }
        }
    }
    {   // outer relu applied here
        float4 r;
        r.x = fmaxf(c0[0], 0.f); r.y = fmaxf(c0[1], 0.f);
        r.z = fmaxf(c0[2], 0.f); r.w = fmaxf(c0[3], 0.f);
        *(float4*)&sm[O2_OFF + l * PAD_R + wq * 8] = r;
        r.x = fmaxf(c0[4], 0.f); r.y = fmaxf(c0[5], 0.f);
        r.z = fmaxf(c0[6], 0.f); r.w = fmaxf(c0[7], 0.f);
        *(float4*)&sm[O2_OFF + l * PAD_R + wq * 8 + 4] = r;
        r.x = fmaxf(c1[0], 0.f); r.y = fmaxf(c1[1], 0.f);
        r.z = fmaxf(c1[2], 0.f); r.w = fmaxf(c1[3], 0.f);
        *(float4*)&sm[O2_OFF + (l + 64) * PAD_R + wq * 8] = r;
        r.x = fmaxf(c1[4], 0.f); r.y = fmaxf(c1[5], 0.f);
        r.z = fmaxf(c1[6], 0.f); r.w = fmaxf(c1[7], 0.f);
        *(float4*)&sm[O2_OFF + (l + 64) * PAD_R + wq * 8 + 4] = r;
    }
    __syncthreads();

#pragma unroll 1
    for (int p = 0; p < 16; ++p) {
        const int m = wq + 8 * p;
        const int n = n0 + m;
        if (n < N) hout[(size_t)n * H + l] = sm[O2_OFF + m * PAD_R + l];
    }
}

// ---------------- pool + head (unchanged from v1, tiny) ----------------
__global__ void pool_kernel(const float* __restrict__ h,
                            const int* __restrict__ batch,
                            float* __restrict__ pooled,
                            float* __restrict__ counts, int N)
{
    int t = blockIdx.x * blockDim.x + threadIdx.x;
    int n = t >> 6, lane = t & 63;
    if (n >= N) return;
    int g = batch[n];
    atomicAdd(&pooled[(size_t)g * H + lane], h[(size_t)n * H + lane]);
    if (lane == 0) atomicAdd(&counts[g], 1.0f);
}

__global__ void head_kernel(const float* __restrict__ pooled,
                            const float* __restrict__ counts,
                            const float* __restrict__ lin1w,
                            const float* __restrict__ lin1b,
                            const float* __restrict__ lin2w,
                            const float* __restrict__ lin2b,
                            float* __restrict__ out, int G)
{
    int g = blockIdx.x;
    int j = threadIdx.x;
    __shared__ float p[H];
    float c = fmaxf(counts[g], 1.0f);
    p[j] = pooled[(size_t)g * H + j] / c;
    __syncthreads();

    float accj = lin1b[j];
#pragma unroll
    for (int k = 0; k < H; ++k) accj = fmaf(p[k], lin1w[k * H + j], accj);
    accj = fmaxf(accj, 0.0f) * lin2w[j];
#pragma unroll
    for (int off = 32; off >= 1; off >>= 1) accj += __shfl_down(accj, off);
    if (j == 0) out[g] = accj + lin2b[0];
}

extern "C" void kernel_launch(void* const* d_in, const int* in_sizes, int n_in,
                              void* d_out, int out_size, void* d_ws, size_t ws_size,
                              hipStream_t stream)
{
    const float* x      = (const float*)d_in[0];
    const int*   eidx   = (const int*)d_in[1];
    const float* ea     = (const float*)d_in[2];
    const int*   batch  = (const int*)d_in[3];
    const float* mW1    = (const float*)d_in[4];
    const float* mb1    = (const float*)d_in[5];
    const float* mW2    = (const float*)d_in[6];
    const float* mb2    = (const float*)d_in[7];
    const float* uW1    = (const float*)d_in[8];
    const float* ub1    = (const float*)d_in[9];
    const float* uW2    = (const float*)d_in[10];
    const float* ub2    = (const float*)d_in[11];
    const float* lin1w  = (const float*)d_in[12];
    const float* lin1b  = (const float*)d_in[13];
    const float* lin2w  = (const float*)d_in[14];
    const float* lin2b  = (const float*)d_in[15];

    const int N = in_sizes[0] / H;
    const int E = in_sizes[1] / 2;
    const int G = out_size;

    float* hA     = (float*)d_ws;
    float* hB     = hA + (size_t)N * H;
    float* agg    = hB + (size_t)N * H;
    float* pooled = agg + (size_t)N * H;
    float* counts = pooled + (size_t)G * H;

    const int* esrc = eidx;
    const int* edst = eidx + E;

    const float* hin = x;
    float* houts[3] = {hA, hB, hA};

    const size_t smE = 128 * PAD_E * sizeof(float);  // 75776 B
    const size_t smN = 128 * PAD_N * sizeof(float);  // 71680 B
    const int nEB = (E + ME - 1) / ME;               // 6250 (exact)
    const int nNB = (N + ME - 1) / ME;

    for (int l = 0; l < 3; ++l) {
        hipMemsetAsync(agg, 0, (size_t)N * H * sizeof(float), stream);
        edge_msg_kernel<<<nEB, 512, smE, stream>>>(
            hin, esrc, edst, ea,
            mW1 + (size_t)l * 144 * H, mb1 + (size_t)l * H,
            mW2 + (size_t)l * H * H,   mb2 + (size_t)l * H,
            agg, E);
        node_update_kernel<<<nNB, 512, smN, stream>>>(
            hin, agg,
            uW1 + (size_t)l * 128 * H, ub1 + (size_t)l * H,
            uW2 + (size_t)l * H * H,   ub2 + (size_t)l * H,
            houts[l], N);
        hin = houts[l];
    }

    hipMemsetAsync(pooled, 0, ((size_t)G * H + G) * sizeof(float), stream);
    pool_kernel<<<((size_t)N * H + 255) / 256, 256, 0, stream>>>(hin, batch, pooled, counts, N);
    head_kernel<<<G, H, 0, stream>>>(pooled, counts, lin1w, lin1b, lin2w, lin2b,
                                     (float*)d_out, G);
}

// Round 3
// 930.566 us; speedup vs baseline: 9.3886x; 1.4845x over previous
//
#include <hip/hip_runtime.h>

#define H 64

typedef __attribute__((ext_vector_type(8))) short short8;
typedef __attribute__((ext_vector_type(4))) float floatx4;

// round-to-nearest-even fp32 -> bf16 (as raw bits in short)
__device__ __forceinline__ short bf16r(float f) {
    union { float f; unsigned u; } v; v.f = f;
    unsigned r = v.u + 0x7FFFu + ((v.u >> 16) & 1u);
    return (short)(r >> 16);
}

// LDS layout (dynamic):
//   [0, 40960)        : A-tile bf16 fragments, [kt][mt(8)][lane(64)][8 bf16] (16B/lane, contiguous)
//   [40960, 74752)    : Cbuf fp32 [128][CSTR]; CSTR=66 -> 4*66 = 264 = 8 mod 32 per quad-step
//                       => every b32 access pattern below hits each bank exactly twice (free)
#define CB_OFF 40960
#define CSTR 66
#define SMEM_BYTES (CB_OFF + 128 * CSTR * 4)   // 74752 B -> 2 blocks/CU

// ---- weight prep: pack W[L][K][64] fp32 -> bf16 MFMA B-fragments [L][KT][4][64][8] ----
// B-operand layout (verified): lane holds B[k = kt*32 + (lane>>4)*8 + j][n = nt*16 + (lane&15)]
__global__ void prep_frag(const float* __restrict__ W, short* __restrict__ out,
                          int K, int KT, int total)
{
    int tid = blockIdx.x * blockDim.x + threadIdx.x;
    if (tid >= total) return;
    const int lane = tid & 63;
    const int nt = (tid >> 6) & 3;
    const int lk = tid >> 8;          // lay*KT + kt
    const int kt = lk % KT;
    const int lay = lk / KT;
    const int n = nt * 16 + (lane & 15);
    const int kbase = kt * 32 + ((lane >> 4) & 3) * 8;
    short8 v;
#pragma unroll
    for (int j = 0; j < 8; ++j) {
        const int k = kbase + j;
        const float w = (k < K) ? W[((size_t)lay * K + k) * H + n] : 0.f;
        v[j] = bf16r(w);
    }
    *(short8*)(out + (size_t)tid * 8) = v;
}

// ---- fused edge-message MLP (MFMA) + coalesced atomic scatter ----
// block = 512 thr (8 waves), M-tile = 128 edges. Wave w owns M16-tile w, all 4 N16-tiles.
__global__ __launch_bounds__(512, 4)
void edge_msg_mfma(const float* __restrict__ hin,
                   const int* __restrict__ esrc,
                   const int* __restrict__ edst,
                   const float* __restrict__ ea,
                   const short* __restrict__ W1f,  // [5][4][64][8] bf16 frags (K=144 zero-padded to 160)
                   const float* __restrict__ b1,
                   const short* __restrict__ W2f,  // [2][4][64][8]
                   const float* __restrict__ b2,
                   float* __restrict__ agg)
{
    extern __shared__ char smraw[];
    short* smA = (short*)smraw;
    float* smC = (float*)(smraw + CB_OFF);

    const int t = threadIdx.x;
    const int e0 = blockIdx.x * 128;
    const int m15 = t & 15, q = (t >> 4) & 3, w = t >> 6;
    const int l = t & 63;
    const int m = w * 16 + m15;       // staging row this thread feeds

    // ---- stage A = cat[h[dst], h[src], ea] as bf16 A-fragments ----
    // chunk (kt, mt=w, lane'=(q<<4)|m15) -> LDS offset (kt*512 + t)*16B : contiguous per wave
    {
        const int d = edst[e0 + m];
        const int s = esrc[e0 + m];
#pragma unroll
        for (int kt = 0; kt < 5; ++kt) {
            const int k0 = kt * 32 + q * 8;
            float f[8];
            if (k0 < 64) {
                const float4 a = *(const float4*)&hin[(size_t)d * H + k0];
                const float4 b = *(const float4*)&hin[(size_t)d * H + k0 + 4];
                f[0] = a.x; f[1] = a.y; f[2] = a.z; f[3] = a.w;
                f[4] = b.x; f[5] = b.y; f[6] = b.z; f[7] = b.w;
            } else if (k0 < 128) {
                const float4 a = *(const float4*)&hin[(size_t)s * H + (k0 - 64)];
                const float4 b = *(const float4*)&hin[(size_t)s * H + (k0 - 60)];
                f[0] = a.x; f[1] = a.y; f[2] = a.z; f[3] = a.w;
                f[4] = b.x; f[5] = b.y; f[6] = b.z; f[7] = b.w;
            } else if (k0 < 144) {
                const float4 a = *(const float4*)&ea[(size_t)(e0 + m) * 16 + (k0 - 128)];
                const float4 b = *(const float4*)&ea[(size_t)(e0 + m) * 16 + (k0 - 124)];
                f[0] = a.x; f[1] = a.y; f[2] = a.z; f[3] = a.w;
                f[4] = b.x; f[5] = b.y; f[6] = b.z; f[7] = b.w;
            } else {
#pragma unroll
                for (int j = 0; j < 8; ++j) f[j] = 0.f;
            }
            short8 v;
#pragma unroll
            for (int j = 0; j < 8; ++j) v[j] = bf16r(f[j]);
            *(short8*)(smA + ((size_t)kt * 512 + t) * 8) = v;
        }
    }
    __syncthreads();

    // ---- GEMM1: [128 x 160] @ W1f -> C1, fp32 acc ----
    floatx4 acc[4] = {{0.f,0.f,0.f,0.f},{0.f,0.f,0.f,0.f},{0.f,0.f,0.f,0.f},{0.f,0.f,0.f,0.f}};
#pragma unroll
    for (int kt = 0; kt < 5; ++kt) {
        const short8 a = *(const short8*)(smA + ((size_t)(kt * 8 + w) * 64 + l) * 8);
#pragma unroll
        for (int nt = 0; nt < 4; ++nt) {
            const short8 b = *(const short8*)(W1f + ((size_t)(kt * 4 + nt) * 64 + l) * 8);
            acc[nt] = __builtin_amdgcn_mfma_f32_16x16x32_bf16(a, b, acc[nt], 0, 0, 0);
        }
    }
    // C/D layout: col n = nt*16 + (l&15), row m = w*16 + (l>>4)*4 + r
#pragma unroll
    for (int nt = 0; nt < 4; ++nt) {
        const float bb = b1[nt * 16 + m15];
#pragma unroll
        for (int r = 0; r < 4; ++r)
            smC[(w * 16 + q * 4 + r) * CSTR + nt * 16 + m15] = fmaxf(acc[nt][r] + bb, 0.f);
    }
    __syncthreads();

    // ---- restage relu(C1) as bf16 A-fragments for GEMM2 (K=64 -> 2 ktiles) ----
#pragma unroll
    for (int i = 0; i < 2; ++i) {
        const int k0 = i * 32 + q * 8;
        short8 v;
#pragma unroll
        for (int j = 0; j < 8; ++j) v[j] = bf16r(smC[m * CSTR + k0 + j]);
        *(short8*)(smA + ((size_t)i * 512 + t) * 8) = v;
    }
    __syncthreads();

    // ---- GEMM2: [128 x 64] @ W2f -> messages ----
    floatx4 c2[4] = {{0.f,0.f,0.f,0.f},{0.f,0.f,0.f,0.f},{0.f,0.f,0.f,0.f},{0.f,0.f,0.f,0.f}};
#pragma unroll
    for (int kt = 0; kt < 2; ++kt) {
        const short8 a = *(const short8*)(smA + ((size_t)(kt * 8 + w) * 64 + l) * 8);
#pragma unroll
        for (int nt = 0; nt < 4; ++nt) {
            const short8 b = *(const short8*)(W2f + ((size_t)(kt * 4 + nt) * 64 + l) * 8);
            c2[nt] = __builtin_amdgcn_mfma_f32_16x16x32_bf16(a, b, c2[nt], 0, 0, 0);
        }
    }
#pragma unroll
    for (int nt = 0; nt < 4; ++nt) {
        const float bb = b2[nt * 16 + m15];
#pragma unroll
        for (int r = 0; r < 4; ++r)
            smC[(w * 16 + q * 4 + r) * CSTR + nt * 16 + m15] = c2[nt][r] + bb;
    }
    // rows w*16..w*16+15 written entirely by this wave -> no barrier needed

    // ---- coalesced atomic scatter: wave = one edge row, lanes = 64 cols ----
#pragma unroll 1
    for (int r = 0; r < 16; ++r) {
        const int mm = w * 16 + r;
        const int d = edst[e0 + mm];
        atomicAdd(&agg[(size_t)d * H + l], smC[mm * CSTR + l]);
    }
}

// ---- fused node-update MLP (MFMA), K=128, coalesced store ----
__global__ __launch_bounds__(512, 4)
void node_update_mfma(const float* __restrict__ hin,
                      const float* __restrict__ agg,
                      const short* __restrict__ W1f,  // [4][4][64][8]
                      const float* __restrict__ b1,
                      const short* __restrict__ W2f,  // [2][4][64][8]
                      const float* __restrict__ b2,
                      float* __restrict__ hout, int N)
{
    extern __shared__ char smraw[];
    short* smA = (short*)smraw;
    float* smC = (float*)(smraw + CB_OFF);

    const int t = threadIdx.x;
    const int n0 = blockIdx.x * 128;
    const int m15 = t & 15, q = (t >> 4) & 3, w = t >> 6;
    const int l = t & 63;
    const int m = w * 16 + m15;

    {
        const int n = n0 + m;
        const bool ok = n < N;
#pragma unroll
        for (int kt = 0; kt < 4; ++kt) {
            const int k0 = kt * 32 + q * 8;
            float f[8];
            if (ok) {
                const float* src = (k0 < 64) ? &hin[(size_t)n * H + k0]
                                             : &agg[(size_t)n * H + (k0 - 64)];
                const float4 a = *(const float4*)src;
                const float4 b = *(const float4*)(src + 4);
                f[0] = a.x; f[1] = a.y; f[2] = a.z; f[3] = a.w;
                f[4] = b.x; f[5] = b.y; f[6] = b.z; f[7] = b.w;
            } else {
#pragma unroll
                for (int j = 0; j < 8; ++j) f[j] = 0.f;
            }
            short8 v;
#pragma unroll
            for (int j = 0; j < 8; ++j) v[j] = bf16r(f[j]);
            *(short8*)(smA + ((size_t)kt * 512 + t) * 8) = v;
        }
    }
    __syncthreads();

    floatx4 acc[4] = {{0.f,0.f,0.f,0.f},{0.f,0.f,0.f,0.f},{0.f,0.f,0.f,0.f},{0.f,0.f,0.f,0.f}};
#pragma unroll
    for (int kt = 0; kt < 4; ++kt) {
        const short8 a = *(const short8*)(smA + ((size_t)(kt * 8 + w) * 64 + l) * 8);
#pragma unroll
        for (int nt = 0; nt < 4; ++nt) {
            const short8 b = *(const short8*)(W1f + ((size_t)(kt * 4 + nt) * 64 + l) * 8);
            acc[nt] = __builtin_amdgcn_mfma_f32_16x16x32_bf16(a, b, acc[nt], 0, 0, 0);
        }
    }
#pragma unroll
    for (int nt = 0; nt < 4; ++nt) {
        const float bb = b1[nt * 16 + m15];
#pragma unroll
        for (int r = 0; r < 4; ++r)
            smC[(w * 16 + q * 4 + r) * CSTR + nt * 16 + m15] = fmaxf(acc[nt][r] + bb, 0.f);
    }
    __syncthreads();

#pragma unroll
    for (int i = 0; i < 2; ++i) {
        const int k0 = i * 32 + q * 8;
        short8 v;
#pragma unroll
        for (int j = 0; j < 8; ++j) v[j] = bf16r(smC[m * CSTR + k0 + j]);
        *(short8*)(smA + ((size_t)i * 512 + t) * 8) = v;
    }
    __syncthreads();

    floatx4 c2[4] = {{0.f,0.f,0.f,0.f},{0.f,0.f,0.f,0.f},{0.f,0.f,0.f,0.f},{0.f,0.f,0.f,0.f}};
#pragma unroll
    for (int kt = 0; kt < 2; ++kt) {
        const short8 a = *(const short8*)(smA + ((size_t)(kt * 8 + w) * 64 + l) * 8);
#pragma unroll
        for (int nt = 0; nt < 4; ++nt) {
            const short8 b = *(const short8*)(W2f + ((size_t)(kt * 4 + nt) * 64 + l) * 8);
            c2[nt] = __builtin_amdgcn_mfma_f32_16x16x32_bf16(a, b, c2[nt], 0, 0, 0);
        }
    }
#pragma unroll
    for (int nt = 0; nt < 4; ++nt) {
        const float bb = b2[nt * 16 + m15];
#pragma unroll
        for (int r = 0; r < 4; ++r)  // outer relu of the update MLP
            smC[(w * 16 + q * 4 + r) * CSTR + nt * 16 + m15] = fmaxf(c2[nt][r] + bb, 0.f);
    }

#pragma unroll 1
    for (int r = 0; r < 16; ++r) {
        const int mm = w * 16 + r;
        const int n = n0 + mm;
        if (n < N) hout[(size_t)n * H + l] = smC[mm * CSTR + l];
    }
}

// ---------------- pool + head ----------------
__global__ void pool_kernel(const float* __restrict__ h,
                            const int* __restrict__ batch,
                            float* __restrict__ pooled,
                            float* __restrict__ counts, int N)
{
    int t = blockIdx.x * blockDim.x + threadIdx.x;
    int n = t >> 6, lane = t & 63;
    if (n >= N) return;
    int g = batch[n];
    atomicAdd(&pooled[(size_t)g * H + lane], h[(size_t)n * H + lane]);
    if (lane == 0) atomicAdd(&counts[g], 1.0f);
}

__global__ void head_kernel(const float* __restrict__ pooled,
                            const float* __restrict__ counts,
                            const float* __restrict__ lin1w,
                            const float* __restrict__ lin1b,
                            const float* __restrict__ lin2w,
                            const float* __restrict__ lin2b,
                            float* __restrict__ out, int G)
{
    int g = blockIdx.x;
    int j = threadIdx.x;
    __shared__ float p[H];
    float c = fmaxf(counts[g], 1.0f);
    p[j] = pooled[(size_t)g * H + j] / c;
    __syncthreads();

    float accj = lin1b[j];
#pragma unroll
    for (int k = 0; k < H; ++k) accj = fmaf(p[k], lin1w[k * H + j], accj);
    accj = fmaxf(accj, 0.0f) * lin2w[j];
#pragma unroll
    for (int off = 32; off >= 1; off >>= 1) accj += __shfl_down(accj, off);
    if (j == 0) out[g] = accj + lin2b[0];
}

extern "C" void kernel_launch(void* const* d_in, const int* in_sizes, int n_in,
                              void* d_out, int out_size, void* d_ws, size_t ws_size,
                              hipStream_t stream)
{
    const float* x      = (const float*)d_in[0];
    const int*   eidx   = (const int*)d_in[1];
    const float* ea     = (const float*)d_in[2];
    const int*   batch  = (const int*)d_in[3];
    const float* mW1    = (const float*)d_in[4];
    const float* mb1    = (const float*)d_in[5];
    const float* mW2    = (const float*)d_in[6];
    const float* mb2    = (const float*)d_in[7];
    const float* uW1    = (const float*)d_in[8];
    const float* ub1    = (const float*)d_in[9];
    const float* uW2    = (const float*)d_in[10];
    const float* ub2    = (const float*)d_in[11];
    const float* lin1w  = (const float*)d_in[12];
    const float* lin1b  = (const float*)d_in[13];
    const float* lin2w  = (const float*)d_in[14];
    const float* lin2b  = (const float*)d_in[15];

    const int N = in_sizes[0] / H;
    const int E = in_sizes[1] / 2;
    const int G = out_size;

    // workspace: bf16 fragment buffers first (16B-aligned sizes), then fp32 buffers
    short* mW1f = (short*)d_ws;                 // 3 * 5*4*64*8 = 30720 shorts
    short* mW2f = mW1f + 30720;                 // 3 * 2*4*64*8 = 12288
    short* uW1f = mW2f + 12288;                 // 3 * 4*4*64*8 = 24576
    short* uW2f = uW1f + 24576;                 // 12288 -> total 79872 shorts = 159744 B
    float* fbase  = (float*)((char*)d_ws + 159744);
    float* hA     = fbase;
    float* hB     = hA + (size_t)N * H;
    float* agg    = hB + (size_t)N * H;
    float* pooled = agg + (size_t)N * H;
    float* counts = pooled + (size_t)G * H;

    const int* esrc = eidx;
    const int* edst = eidx + E;

    // pack weights into MFMA B-fragment order (bf16)
    prep_frag<<<(3*5*4*64 + 255) / 256, 256, 0, stream>>>(mW1, mW1f, 144, 5, 3*5*4*64);
    prep_frag<<<(3*2*4*64 + 255) / 256, 256, 0, stream>>>(mW2, mW2f,  64, 2, 3*2*4*64);
    prep_frag<<<(3*4*4*64 + 255) / 256, 256, 0, stream>>>(uW1, uW1f, 128, 4, 3*4*4*64);
    prep_frag<<<(3*2*4*64 + 255) / 256, 256, 0, stream>>>(uW2, uW2f,  64, 2, 3*2*4*64);

    const float* hin = x;
    float* houts[3] = {hA, hB, hA};
    const int nEB = E / 128;                    // 800000/128 = 6250 exact
    const int nNB = (N + 127) / 128;

    for (int lyr = 0; lyr < 3; ++lyr) {
        hipMemsetAsync(agg, 0, (size_t)N * H * sizeof(float), stream);
        edge_msg_mfma<<<nEB, 512, SMEM_BYTES, stream>>>(
            hin, esrc, edst, ea,
            mW1f + (size_t)lyr * 10240, mb1 + (size_t)lyr * H,
            mW2f + (size_t)lyr * 4096,  mb2 + (size_t)lyr * H,
            agg);
        node_update_mfma<<<nNB, 512, SMEM_BYTES, stream>>>(
            hin, agg,
            uW1f + (size_t)lyr * 8192, ub1 + (size_t)lyr * H,
            uW2f + (size_t)lyr * 4096, ub2 + (size_t)lyr * H,
            houts[lyr], N);
        hin = houts[lyr];
    }

    hipMemsetAsync(pooled, 0, ((size_t)G * H + G) * sizeof(float), stream);
    pool_kernel<<<((size_t)N * H + 255) / 256, 256, 0, stream>>>(hin, batch, pooled, counts, N);
    head_kernel<<<G, H, 0, stream>>>(pooled, counts, lin1w, lin1b, lin2w, lin2b,
                                     (float*)d_out, G);
}

// Round 4
// 824.171 us; speedup vs baseline: 10.6006x; 1.1291x over previous
//
#include <hip/hip_runtime.h>

#define H 64

typedef __attribute__((ext_vector_type(8))) short short8;
typedef __attribute__((ext_vector_type(4))) float floatx4;

__device__ __forceinline__ short bf16r(float f) {
    union { float f; unsigned u; } v; v.f = f;
    unsigned r = v.u + 0x7FFFu + ((v.u >> 16) & 1u);
    return (short)(r >> 16);
}

// LDS: [0, 40960) A-frags bf16; [40960, 74752) Cbuf fp32 [128][66]
#define CB_OFF 40960
#define CSTR 66
#define SMEM_E (CB_OFF + 128 * CSTR * 4)          // 74752 B
// node kernel: A-frags 16KB + C 64*66*4
#define CB_OFF_N 16384
#define SMEM_N (CB_OFF_N + 64 * CSTR * 4)         // 33280 B

// ---- weight prep: W[L][K][64] fp32 -> bf16 B-fragments [L][KT][4][64][8] ----
__global__ void prep_frag(const float* __restrict__ W, short* __restrict__ out,
                          int K, int KT, int total)
{
    int tid = blockIdx.x * blockDim.x + threadIdx.x;
    if (tid >= total) return;
    const int lane = tid & 63;
    const int nt = (tid >> 6) & 3;
    const int lk = tid >> 8;
    const int kt = lk % KT;
    const int lay = lk / KT;
    const int n = nt * 16 + (lane & 15);
    const int kbase = kt * 32 + ((lane >> 4) & 3) * 8;
    short8 v;
#pragma unroll
    for (int j = 0; j < 8; ++j) {
        const int k = kbase + j;
        const float w = (k < K) ? W[((size_t)lay * K + k) * H + n] : 0.f;
        v[j] = bf16r(w);
    }
    *(short8*)(out + (size_t)tid * 8) = v;
}

// ---- sort prep: histogram, scan, permutation, gather ----
__global__ void hist_kernel(const int* __restrict__ edst, int* __restrict__ cnt, int E)
{
    int e = blockIdx.x * blockDim.x + threadIdx.x;
    if (e < E) atomicAdd(&cnt[edst[e]], 1);
}

__global__ void scan_kernel(const int* __restrict__ cnt, int* __restrict__ offs, int n)
{
    __shared__ int buf[1024];
    __shared__ int carry;
    const int t = threadIdx.x;
    if (t == 0) carry = 0;
    __syncthreads();
    for (int base = 0; base < n; base += 1024) {
        const int i = base + t;
        const int v = (i < n) ? cnt[i] : 0;
        buf[t] = v;
        __syncthreads();
#pragma unroll
        for (int off = 1; off < 1024; off <<= 1) {
            int x = (t >= off) ? buf[t - off] : 0;
            __syncthreads();
            buf[t] += x;
            __syncthreads();
        }
        if (i < n) offs[i] = carry + buf[t] - v;   // exclusive
        __syncthreads();
        if (t == 1023) carry += buf[1023];
        __syncthreads();
    }
}

__global__ void build_perm(const int* __restrict__ edst, int* __restrict__ offs,
                           int* __restrict__ eperm, int E)
{
    int e = blockIdx.x * blockDim.x + threadIdx.x;
    if (e >= E) return;
    const int d = edst[e];
    const int p = atomicAdd(&offs[d], 1);
    eperm[p] = e;
}

__global__ void gather_sd(const int* __restrict__ eperm,
                          const int* __restrict__ esrc, const int* __restrict__ edst,
                          int* __restrict__ src_s, int* __restrict__ dst_s, int E)
{
    int i = blockIdx.x * blockDim.x + threadIdx.x;
    if (i >= E) return;
    const int p = eperm[i];
    src_s[i] = esrc[p];
    dst_s[i] = edst[p];
}

// ---- fused edge-message MLP (MFMA) over dst-sorted edges + run-merged scatter ----
__global__ __launch_bounds__(512, 4)
void edge_msg_mfma(const float* __restrict__ hin,
                   const int* __restrict__ src_s,
                   const int* __restrict__ dst_s,
                   const int* __restrict__ eperm,
                   const float* __restrict__ ea,
                   const short* __restrict__ W1f, const float* __restrict__ b1,
                   const short* __restrict__ W2f, const float* __restrict__ b2,
                   float* __restrict__ agg)
{
    extern __shared__ char smraw[];
    short* smA = (short*)smraw;
    float* smC = (float*)(smraw + CB_OFF);

    const int t = threadIdx.x;
    const int e0 = blockIdx.x * 128;
    const int m15 = t & 15, q = (t >> 4) & 3, w = t >> 6;
    const int l = t & 63;
    const int m = w * 16 + m15;

    // ---- stage A = cat[h[dst], h[src], ea[perm]] as bf16 A-fragments ----
    {
        const int i = e0 + m;
        const int d = dst_s[i];
        const int s = src_s[i];
        const int ep = eperm[i];
#pragma unroll
        for (int kt = 0; kt < 5; ++kt) {
            const int k0 = kt * 32 + q * 8;
            float f[8];
            if (k0 < 64) {
                const float4 a = *(const float4*)&hin[(size_t)d * H + k0];
                const float4 b = *(const float4*)&hin[(size_t)d * H + k0 + 4];
                f[0] = a.x; f[1] = a.y; f[2] = a.z; f[3] = a.w;
                f[4] = b.x; f[5] = b.y; f[6] = b.z; f[7] = b.w;
            } else if (k0 < 128) {
                const float4 a = *(const float4*)&hin[(size_t)s * H + (k0 - 64)];
                const float4 b = *(const float4*)&hin[(size_t)s * H + (k0 - 60)];
                f[0] = a.x; f[1] = a.y; f[2] = a.z; f[3] = a.w;
                f[4] = b.x; f[5] = b.y; f[6] = b.z; f[7] = b.w;
            } else if (k0 < 144) {
                const float4 a = *(const float4*)&ea[(size_t)ep * 16 + (k0 - 128)];
                const float4 b = *(const float4*)&ea[(size_t)ep * 16 + (k0 - 124)];
                f[0] = a.x; f[1] = a.y; f[2] = a.z; f[3] = a.w;
                f[4] = b.x; f[5] = b.y; f[6] = b.z; f[7] = b.w;
            } else {
#pragma unroll
                for (int j = 0; j < 8; ++j) f[j] = 0.f;
            }
            short8 v;
#pragma unroll
            for (int j = 0; j < 8; ++j) v[j] = bf16r(f[j]);
            *(short8*)(smA + ((size_t)kt * 512 + t) * 8) = v;
        }
    }
    __syncthreads();

    // ---- GEMM1 ----
    floatx4 acc[4] = {{0.f,0.f,0.f,0.f},{0.f,0.f,0.f,0.f},{0.f,0.f,0.f,0.f},{0.f,0.f,0.f,0.f}};
#pragma unroll
    for (int kt = 0; kt < 5; ++kt) {
        const short8 a = *(const short8*)(smA + ((size_t)(kt * 8 + w) * 64 + l) * 8);
#pragma unroll
        for (int nt = 0; nt < 4; ++nt) {
            const short8 b = *(const short8*)(W1f + ((size_t)(kt * 4 + nt) * 64 + l) * 8);
            acc[nt] = __builtin_amdgcn_mfma_f32_16x16x32_bf16(a, b, acc[nt], 0, 0, 0);
        }
    }
#pragma unroll
    for (int nt = 0; nt < 4; ++nt) {
        const float bb = b1[nt * 16 + m15];
#pragma unroll
        for (int r = 0; r < 4; ++r)
            smC[(w * 16 + q * 4 + r) * CSTR + nt * 16 + m15] = fmaxf(acc[nt][r] + bb, 0.f);
    }
    __syncthreads();

    // ---- restage relu(C1) as A-frags (K=64) ----
#pragma unroll
    for (int i = 0; i < 2; ++i) {
        const int k0 = i * 32 + q * 8;
        short8 v;
#pragma unroll
        for (int j = 0; j < 8; ++j) v[j] = bf16r(smC[m * CSTR + k0 + j]);
        *(short8*)(smA + ((size_t)i * 512 + t) * 8) = v;
    }
    __syncthreads();

    // ---- GEMM2 ----
    floatx4 c2[4] = {{0.f,0.f,0.f,0.f},{0.f,0.f,0.f,0.f},{0.f,0.f,0.f,0.f},{0.f,0.f,0.f,0.f}};
#pragma unroll
    for (int kt = 0; kt < 2; ++kt) {
        const short8 a = *(const short8*)(smA + ((size_t)(kt * 8 + w) * 64 + l) * 8);
#pragma unroll
        for (int nt = 0; nt < 4; ++nt) {
            const short8 b = *(const short8*)(W2f + ((size_t)(kt * 4 + nt) * 64 + l) * 8);
            c2[nt] = __builtin_amdgcn_mfma_f32_16x16x32_bf16(a, b, c2[nt], 0, 0, 0);
        }
    }
#pragma unroll
    for (int nt = 0; nt < 4; ++nt) {
        const float bb = b2[nt * 16 + m15];
#pragma unroll
        for (int r = 0; r < 4; ++r)
            smC[(w * 16 + q * 4 + r) * CSTR + nt * 16 + m15] = c2[nt][r] + bb;
    }
    // rows w*16..w*16+15 produced and consumed by this wave only

    // ---- run-merged scatter: dst-sorted rows -> one atomic row per run ----
    {
        int cur = __builtin_amdgcn_readfirstlane(dst_s[e0 + w * 16]);
        float run = smC[(w * 16) * CSTR + l];
#pragma unroll 1
        for (int r = 1; r < 16; ++r) {
            const int mm = w * 16 + r;
            const int d = __builtin_amdgcn_readfirstlane(dst_s[e0 + mm]);
            const float v = smC[mm * CSTR + l];
            if (d != cur) {
                atomicAdd(&agg[(size_t)cur * H + l], run);
                run = v; cur = d;
            } else {
                run += v;
            }
        }
        atomicAdd(&agg[(size_t)cur * H + l], run);
    }
}

// ---- node-update MLP (MFMA), M-tile 64, 256 threads, 4 blocks/CU ----
__global__ __launch_bounds__(256, 4)
void node_update_mfma(const float* __restrict__ hin,
                      const float* __restrict__ agg,
                      const short* __restrict__ W1f, const float* __restrict__ b1,
                      const short* __restrict__ W2f, const float* __restrict__ b2,
                      float* __restrict__ hout, int N)
{
    extern __shared__ char smraw[];
    short* smA = (short*)smraw;
    float* smC = (float*)(smraw + CB_OFF_N);

    const int t = threadIdx.x;
    const int n0 = blockIdx.x * 64;
    const int m15 = t & 15, q = (t >> 4) & 3, w = t >> 6;   // w in 0..3
    const int l = t & 63;
    const int m = w * 16 + m15;

    {
        const int n = n0 + m;
        const bool ok = n < N;
#pragma unroll
        for (int kt = 0; kt < 4; ++kt) {
            const int k0 = kt * 32 + q * 8;
            float f[8];
            if (ok) {
                const float* src = (k0 < 64) ? &hin[(size_t)n * H + k0]
                                             : &agg[(size_t)n * H + (k0 - 64)];
                const float4 a = *(const float4*)src;
                const float4 b = *(const float4*)(src + 4);
                f[0] = a.x; f[1] = a.y; f[2] = a.z; f[3] = a.w;
                f[4] = b.x; f[5] = b.y; f[6] = b.z; f[7] = b.w;
            } else {
#pragma unroll
                for (int j = 0; j < 8; ++j) f[j] = 0.f;
            }
            short8 v;
#pragma unroll
            for (int j = 0; j < 8; ++j) v[j] = bf16r(f[j]);
            *(short8*)(smA + ((size_t)kt * 256 + t) * 8) = v;
        }
    }
    __syncthreads();

    floatx4 acc[4] = {{0.f,0.f,0.f,0.f},{0.f,0.f,0.f,0.f},{0.f,0.f,0.f,0.f},{0.f,0.f,0.f,0.f}};
#pragma unroll
    for (int kt = 0; kt < 4; ++kt) {
        const short8 a = *(const short8*)(smA + ((size_t)(kt * 4 + w) * 64 + l) * 8);
#pragma unroll
        for (int nt = 0; nt < 4; ++nt) {
            const short8 b = *(const short8*)(W1f + ((size_t)(kt * 4 + nt) * 64 + l) * 8);
            acc[nt] = __builtin_amdgcn_mfma_f32_16x16x32_bf16(a, b, acc[nt], 0, 0, 0);
        }
    }
#pragma unroll
    for (int nt = 0; nt < 4; ++nt) {
        const float bb = b1[nt * 16 + m15];
#pragma unroll
        for (int r = 0; r < 4; ++r)
            smC[(w * 16 + q * 4 + r) * CSTR + nt * 16 + m15] = fmaxf(acc[nt][r] + bb, 0.f);
    }
    __syncthreads();

#pragma unroll
    for (int i = 0; i < 2; ++i) {
        const int k0 = i * 32 + q * 8;
        short8 v;
#pragma unroll
        for (int j = 0; j < 8; ++j) v[j] = bf16r(smC[m * CSTR + k0 + j]);
        *(short8*)(smA + ((size_t)i * 256 + t) * 8) = v;
    }
    __syncthreads();

    floatx4 c2[4] = {{0.f,0.f,0.f,0.f},{0.f,0.f,0.f,0.f},{0.f,0.f,0.f,0.f},{0.f,0.f,0.f,0.f}};
#pragma unroll
    for (int kt = 0; kt < 2; ++kt) {
        const short8 a = *(const short8*)(smA + ((size_t)(kt * 4 + w) * 64 + l) * 8);
#pragma unroll
        for (int nt = 0; nt < 4; ++nt) {
            const short8 b = *(const short8*)(W2f + ((size_t)(kt * 4 + nt) * 64 + l) * 8);
            c2[nt] = __builtin_amdgcn_mfma_f32_16x16x32_bf16(a, b, c2[nt], 0, 0, 0);
        }
    }
#pragma unroll
    for (int nt = 0; nt < 4; ++nt) {
        const float bb = b2[nt * 16 + m15];
#pragma unroll
        for (int r = 0; r < 4; ++r)
            smC[(w * 16 + q * 4 + r) * CSTR + nt * 16 + m15] = fmaxf(c2[nt][r] + bb, 0.f);
    }

#pragma unroll 1
    for (int r = 0; r < 16; ++r) {
        const int mm = w * 16 + r;
        const int n = n0 + mm;
        if (n < N) hout[(size_t)n * H + l] = smC[mm * CSTR + l];
    }
}

// ---- pool: batch_idx is sorted -> per-wave run merge over 32 nodes ----
__global__ void pool_kernel(const float* __restrict__ h,
                            const int* __restrict__ batch,
                            float* __restrict__ pooled,
                            float* __restrict__ counts, int N)
{
    const int t = blockIdx.x * blockDim.x + threadIdx.x;
    const int wave = t >> 6, l = t & 63;
    const int base = wave * 32;
    if (base >= N) return;
    const int end = (base + 32 < N) ? base + 32 : N;
    int cur = __builtin_amdgcn_readfirstlane(batch[base]);
    float run = h[(size_t)base * H + l];
    int c = 1;
#pragma unroll 1
    for (int n = base + 1; n < end; ++n) {
        const int b = __builtin_amdgcn_readfirstlane(batch[n]);
        const float v = h[(size_t)n * H + l];
        if (b != cur) {
            atomicAdd(&pooled[(size_t)cur * H + l], run);
            if (l == 0) atomicAdd(&counts[cur], (float)c);
            run = v; cur = b; c = 1;
        } else { run += v; ++c; }
    }
    atomicAdd(&pooled[(size_t)cur * H + l], run);
    if (l == 0) atomicAdd(&counts[cur], (float)c);
}

__global__ void head_kernel(const float* __restrict__ pooled,
                            const float* __restrict__ counts,
                            const float* __restrict__ lin1w,
                            const float* __restrict__ lin1b,
                            const float* __restrict__ lin2w,
                            const float* __restrict__ lin2b,
                            float* __restrict__ out, int G)
{
    int g = blockIdx.x;
    int j = threadIdx.x;
    __shared__ float p[H];
    float c = fmaxf(counts[g], 1.0f);
    p[j] = pooled[(size_t)g * H + j] / c;
    __syncthreads();

    float accj = lin1b[j];
#pragma unroll
    for (int k = 0; k < H; ++k) accj = fmaf(p[k], lin1w[k * H + j], accj);
    accj = fmaxf(accj, 0.0f) * lin2w[j];
#pragma unroll
    for (int off = 32; off >= 1; off >>= 1) accj += __shfl_down(accj, off);
    if (j == 0) out[g] = accj + lin2b[0];
}

extern "C" void kernel_launch(void* const* d_in, const int* in_sizes, int n_in,
                              void* d_out, int out_size, void* d_ws, size_t ws_size,
                              hipStream_t stream)
{
    const float* x      = (const float*)d_in[0];
    const int*   eidx   = (const int*)d_in[1];
    const float* ea     = (const float*)d_in[2];
    const int*   batch  = (const int*)d_in[3];
    const float* mW1    = (const float*)d_in[4];
    const float* mb1    = (const float*)d_in[5];
    const float* mW2    = (const float*)d_in[6];
    const float* mb2    = (const float*)d_in[7];
    const float* uW1    = (const float*)d_in[8];
    const float* ub1    = (const float*)d_in[9];
    const float* uW2    = (const float*)d_in[10];
    const float* ub2    = (const float*)d_in[11];
    const float* lin1w  = (const float*)d_in[12];
    const float* lin1b  = (const float*)d_in[13];
    const float* lin2w  = (const float*)d_in[14];
    const float* lin2b  = (const float*)d_in[15];

    const int N = in_sizes[0] / H;
    const int E = in_sizes[1] / 2;
    const int G = out_size;

    // ---- workspace layout ----
    short* mW1f = (short*)d_ws;                 // 30720 shorts
    short* mW2f = mW1f + 30720;                 // 12288
    short* uW1f = mW2f + 12288;                 // 24576
    short* uW2f = uW1f + 24576;                 // 12288 -> 159744 B total
    char*  p    = (char*)d_ws + 159744;
    int* cnt    = (int*)p;            p += (size_t)N * 4;
    int* offs   = (int*)p;            p += (size_t)N * 4;
    int* eperm  = (int*)p;            p += (size_t)E * 4;
    int* src_s  = (int*)p;            p += (size_t)E * 4;
    int* dst_s  = (int*)p;            p += (size_t)E * 4;
    float* hA     = (float*)p;
    float* hB     = hA + (size_t)N * H;
    float* agg    = hB + (size_t)N * H;
    float* pooled = agg + (size_t)N * H;
    float* counts = pooled + (size_t)G * H;

    const int* esrc = eidx;
    const int* edst = eidx + E;

    // ---- weight packing ----
    prep_frag<<<(3*5*4*64 + 255) / 256, 256, 0, stream>>>(mW1, mW1f, 144, 5, 3*5*4*64);
    prep_frag<<<(3*2*4*64 + 255) / 256, 256, 0, stream>>>(mW2, mW2f,  64, 2, 3*2*4*64);
    prep_frag<<<(3*4*4*64 + 255) / 256, 256, 0, stream>>>(uW1, uW1f, 128, 4, 3*4*4*64);
    prep_frag<<<(3*2*4*64 + 255) / 256, 256, 0, stream>>>(uW2, uW2f,  64, 2, 3*2*4*64);

    // ---- dst-sort prep (once per call) ----
    hipMemsetAsync(cnt, 0, (size_t)N * 4, stream);
    hist_kernel<<<(E + 255) / 256, 256, 0, stream>>>(edst, cnt, E);
    scan_kernel<<<1, 1024, 0, stream>>>(cnt, offs, N);
    build_perm<<<(E + 255) / 256, 256, 0, stream>>>(edst, offs, eperm, E);
    gather_sd<<<(E + 255) / 256, 256, 0, stream>>>(eperm, esrc, edst, src_s, dst_s, E);

    const float* hin = x;
    float* houts[3] = {hA, hB, hA};
    const int nEB = E / 128;
    const int nNB = (N + 63) / 64;

    for (int lyr = 0; lyr < 3; ++lyr) {
        hipMemsetAsync(agg, 0, (size_t)N * H * sizeof(float), stream);
        edge_msg_mfma<<<nEB, 512, SMEM_E, stream>>>(
            hin, src_s, dst_s, eperm, ea,
            mW1f + (size_t)lyr * 10240, mb1 + (size_t)lyr * H,
            mW2f + (size_t)lyr * 4096,  mb2 + (size_t)lyr * H,
            agg);
        node_update_mfma<<<nNB, 256, SMEM_N, stream>>>(
            hin, agg,
            uW1f + (size_t)lyr * 8192, ub1 + (size_t)lyr * H,
            uW2f + (size_t)lyr * 4096, ub2 + (size_t)lyr * H,
            houts[lyr], N);
        hin = houts[lyr];
    }

    hipMemsetAsync(pooled, 0, ((size_t)G * H + G) * sizeof(float), stream);
    {
        const int waves = (N + 31) / 32;
        pool_kernel<<<(waves * 64 + 255) / 256, 256, 0, stream>>>(hin, batch, pooled, counts, N);
    }
    head_kernel<<<G, H, 0, stream>>>(pooled, counts, lin1w, lin1b, lin2w, lin2b,
                                     (float*)d_out, G);
}

// Round 5
// 709.544 us; speedup vs baseline: 12.3131x; 1.1615x over previous
//
#include <hip/hip_runtime.h>

#define H 64

typedef __attribute__((ext_vector_type(8))) short short8;
typedef __attribute__((ext_vector_type(4))) float floatx4;

__device__ __forceinline__ short bf16r(float f) {
    union { float f; unsigned u; } v; v.f = f;
    unsigned r = v.u + 0x7FFFu + ((v.u >> 16) & 1u);
    return (short)(r >> 16);
}

// edge kernel LDS: [0, 40960) A-frags bf16 [kt(5)][wave(8)][lane(64)][8]; [40960,...) C fp32 [128][66]
#define CB_OFF 40960
#define CSTR 66
#define SMEM_E (CB_OFF + 128 * CSTR * 4)     // 74752 B -> 2 blocks/CU
// node kernel LDS: A-frags [kt(4)][wave(4)][lane(64)][8] = 16384; C fp32 [64][66]
#define CB_OFF_N 16384
#define SMEM_N (CB_OFF_N + 64 * CSTR * 4)    // 33280 B -> 4 blocks/CU

// ---- weight prep: W[L][K][64] fp32 -> bf16 B-fragments [L][KT][4][64][8] ----
__global__ void prep_frag(const float* __restrict__ W, short* __restrict__ out,
                          int K, int KT, int total)
{
    int tid = blockIdx.x * blockDim.x + threadIdx.x;
    if (tid >= total) return;
    const int lane = tid & 63;
    const int nt = (tid >> 6) & 3;
    const int lk = tid >> 8;
    const int kt = lk % KT;
    const int lay = lk / KT;
    const int n = nt * 16 + (lane & 15);
    const int kbase = kt * 32 + ((lane >> 4) & 3) * 8;
    short8 v;
#pragma unroll
    for (int j = 0; j < 8; ++j) {
        const int k = kbase + j;
        const float w = (k < K) ? W[((size_t)lay * K + k) * H + n] : 0.f;
        v[j] = bf16r(w);
    }
    *(short8*)(out + (size_t)tid * 8) = v;
}

// ---- fp32 -> bf16 bulk convert (8 elems/thread) ----
__global__ void to_bf16(const float* __restrict__ in, short* __restrict__ out, int n8)
{
    int i = blockIdx.x * blockDim.x + threadIdx.x;
    if (i >= n8) return;
    const float4 a = ((const float4*)in)[2 * i];
    const float4 b = ((const float4*)in)[2 * i + 1];
    short8 v;
    v[0] = bf16r(a.x); v[1] = bf16r(a.y); v[2] = bf16r(a.z); v[3] = bf16r(a.w);
    v[4] = bf16r(b.x); v[5] = bf16r(b.y); v[6] = bf16r(b.z); v[7] = bf16r(b.w);
    ((short8*)out)[i] = v;
}

// ---- sort prep ----
__global__ void hist_kernel(const int* __restrict__ edst, int* __restrict__ cnt, int E)
{
    int e = blockIdx.x * blockDim.x + threadIdx.x;
    if (e < E) atomicAdd(&cnt[edst[e]], 1);
}

__global__ void scan_block(const int* __restrict__ cnt, int* __restrict__ offs,
                           int* __restrict__ bsum, int n)
{
    __shared__ int buf[1024];
    const int t = threadIdx.x;
    const int gid = blockIdx.x * 1024 + t;
    const int v = (gid < n) ? cnt[gid] : 0;
    buf[t] = v;
    __syncthreads();
#pragma unroll
    for (int off = 1; off < 1024; off <<= 1) {
        int x = (t >= off) ? buf[t - off] : 0;
        __syncthreads();
        buf[t] += x;
        __syncthreads();
    }
    if (gid < n) offs[gid] = buf[t] - v;          // exclusive within block
    if (t == 1023) bsum[blockIdx.x] = buf[1023];
}

__global__ void scan_bsum(int* __restrict__ bsum, int nb)
{
    if (threadIdx.x == 0) {
        int acc = 0;
        for (int i = 0; i < nb; ++i) { int v = bsum[i]; bsum[i] = acc; acc += v; }
    }
}

__global__ void add_bsum(int* __restrict__ offs, const int* __restrict__ bsum, int n)
{
    int gid = blockIdx.x * blockDim.x + threadIdx.x;
    if (gid < n) offs[gid] += bsum[gid >> 10];
}

__global__ void build_perm(const int* __restrict__ edst, int* __restrict__ offs,
                           int* __restrict__ eperm, int E)
{
    int e = blockIdx.x * blockDim.x + threadIdx.x;
    if (e >= E) return;
    const int d = edst[e];
    const int p = atomicAdd(&offs[d], 1);
    eperm[p] = e;
}

// gather src/dst into sorted order + permute edge_attr into sorted bf16
__global__ void gather_edges(const int* __restrict__ eperm,
                             const int* __restrict__ esrc, const int* __restrict__ edst,
                             const float* __restrict__ ea,
                             int* __restrict__ src_s, int* __restrict__ dst_s,
                             short* __restrict__ ea16, int E)
{
    int i = blockIdx.x * blockDim.x + threadIdx.x;
    if (i >= E) return;
    const int p = eperm[i];
    src_s[i] = esrc[p];
    dst_s[i] = edst[p];
    const float4* r = (const float4*)(ea + (size_t)p * 16);
    const float4 a = r[0], b = r[1], c = r[2], d4 = r[3];
    short8 v0, v1;
    v0[0] = bf16r(a.x); v0[1] = bf16r(a.y); v0[2] = bf16r(a.z); v0[3] = bf16r(a.w);
    v0[4] = bf16r(b.x); v0[5] = bf16r(b.y); v0[6] = bf16r(b.z); v0[7] = bf16r(b.w);
    v1[0] = bf16r(c.x); v1[1] = bf16r(c.y); v1[2] = bf16r(c.z); v1[3] = bf16r(c.w);
    v1[4] = bf16r(d4.x); v1[5] = bf16r(d4.y); v1[6] = bf16r(d4.z); v1[7] = bf16r(d4.w);
    short8* o = (short8*)(ea16 + (size_t)i * 16);
    o[0] = v0; o[1] = v1;
}

// ---- fused edge-message MLP (MFMA), dst-sorted, run-merged scatter ----
// NOTE: all LDS regions are wave-private (wave w touches only rows 16w..16w+16)
// -> no __syncthreads anywhere; waves pipeline their gathers independently.
__global__ __launch_bounds__(512, 4)
void edge_msg_mfma(const short* __restrict__ h16,
                   const int* __restrict__ src_s,
                   const int* __restrict__ dst_s,
                   const short* __restrict__ ea16,
                   const short* __restrict__ W1f, const float* __restrict__ b1,
                   const short* __restrict__ W2f, const float* __restrict__ b2,
                   float* __restrict__ agg)
{
    extern __shared__ char smraw[];
    short* smA = (short*)smraw;
    float* smC = (float*)(smraw + CB_OFF);

    const int t = threadIdx.x;
    const int e0 = blockIdx.x * 128;
    const int m15 = t & 15, q = (t >> 4) & 3, w = t >> 6;
    const int l = t & 63;
    const int m = w * 16 + m15;
    const int i = e0 + m;

    // ---- stage A = cat[h16[dst], h16[src], ea16] directly as bf16 A-fragments ----
    {
        const int d = dst_s[i];
        const int s = src_s[i];
        short8 v;
        v = *(const short8*)(h16 + (size_t)d * H + q * 8);
        *(short8*)(smA + ((size_t)0 * 512 + t) * 8) = v;
        v = *(const short8*)(h16 + (size_t)d * H + 32 + q * 8);
        *(short8*)(smA + ((size_t)1 * 512 + t) * 8) = v;
        v = *(const short8*)(h16 + (size_t)s * H + q * 8);
        *(short8*)(smA + ((size_t)2 * 512 + t) * 8) = v;
        v = *(const short8*)(h16 + (size_t)s * H + 32 + q * 8);
        *(short8*)(smA + ((size_t)3 * 512 + t) * 8) = v;
        short8 z = {0, 0, 0, 0, 0, 0, 0, 0};
        v = (q < 2) ? *(const short8*)(ea16 + (size_t)i * 16 + q * 8) : z;
        *(short8*)(smA + ((size_t)4 * 512 + t) * 8) = v;
    }

    // ---- GEMM1: [128 x 160] @ W1f ----
    floatx4 acc[4] = {{0.f,0.f,0.f,0.f},{0.f,0.f,0.f,0.f},{0.f,0.f,0.f,0.f},{0.f,0.f,0.f,0.f}};
#pragma unroll
    for (int kt = 0; kt < 5; ++kt) {
        const short8 a = *(const short8*)(smA + ((size_t)(kt * 8 + w) * 64 + l) * 8);
#pragma unroll
        for (int nt = 0; nt < 4; ++nt) {
            const short8 b = *(const short8*)(W1f + ((size_t)(kt * 4 + nt) * 64 + l) * 8);
            acc[nt] = __builtin_amdgcn_mfma_f32_16x16x32_bf16(a, b, acc[nt], 0, 0, 0);
        }
    }
#pragma unroll
    for (int nt = 0; nt < 4; ++nt) {
        const float bb = b1[nt * 16 + m15];
#pragma unroll
        for (int r = 0; r < 4; ++r)
            smC[(w * 16 + q * 4 + r) * CSTR + nt * 16 + m15] = fmaxf(acc[nt][r] + bb, 0.f);
    }

    // ---- restage relu(C1) as A-frags (K=64) ----
#pragma unroll
    for (int kk = 0; kk < 2; ++kk) {
        const int k0 = kk * 32 + q * 8;
        short8 v;
#pragma unroll
        for (int j = 0; j < 8; ++j) v[j] = bf16r(smC[m * CSTR + k0 + j]);
        *(short8*)(smA + ((size_t)kk * 512 + t) * 8) = v;
    }

    // ---- GEMM2: [128 x 64] @ W2f ----
    floatx4 c2[4] = {{0.f,0.f,0.f,0.f},{0.f,0.f,0.f,0.f},{0.f,0.f,0.f,0.f},{0.f,0.f,0.f,0.f}};
#pragma unroll
    for (int kt = 0; kt < 2; ++kt) {
        const short8 a = *(const short8*)(smA + ((size_t)(kt * 8 + w) * 64 + l) * 8);
#pragma unroll
        for (int nt = 0; nt < 4; ++nt) {
            const short8 b = *(const short8*)(W2f + ((size_t)(kt * 4 + nt) * 64 + l) * 8);
            c2[nt] = __builtin_amdgcn_mfma_f32_16x16x32_bf16(a, b, c2[nt], 0, 0, 0);
        }
    }
#pragma unroll
    for (int nt = 0; nt < 4; ++nt) {
        const float bb = b2[nt * 16 + m15];
#pragma unroll
        for (int r = 0; r < 4; ++r)
            smC[(w * 16 + q * 4 + r) * CSTR + nt * 16 + m15] = c2[nt][r] + bb;
    }

    // ---- run-merged scatter (dst-sorted): one atomic row per run per wave ----
    {
        int cur = __builtin_amdgcn_readfirstlane(dst_s[e0 + w * 16]);
        float run = smC[(w * 16) * CSTR + l];
#pragma unroll 1
        for (int r = 1; r < 16; ++r) {
            const int mm = w * 16 + r;
            const int d = __builtin_amdgcn_readfirstlane(dst_s[e0 + mm]);
            const float v = smC[mm * CSTR + l];
            if (d != cur) {
                atomicAdd(&agg[(size_t)cur * H + l], run);
                run = v; cur = d;
            } else {
                run += v;
            }
        }
        atomicAdd(&agg[(size_t)cur * H + l], run);
    }
}

// ---- node-update MLP (MFMA), M-tile 64, wave-private LDS, no barriers ----
__global__ __launch_bounds__(256, 4)
void node_update_mfma(const short* __restrict__ h16,
                      const float* __restrict__ agg,
                      const short* __restrict__ W1f, const float* __restrict__ b1,
                      const short* __restrict__ W2f, const float* __restrict__ b2,
                      short* __restrict__ h16out, float* __restrict__ hout, int N)
{
    extern __shared__ char smraw[];
    short* smA = (short*)smraw;
    float* smC = (float*)(smraw + CB_OFF_N);

    const int t = threadIdx.x;
    const int n0 = blockIdx.x * 64;
    const int m15 = t & 15, q = (t >> 4) & 3, w = t >> 6;  // w in 0..3
    const int l = t & 63;
    const int m = w * 16 + m15;

    {
        const int n = n0 + m;
        const bool ok = n < N;
        short8 z = {0, 0, 0, 0, 0, 0, 0, 0};
        short8 v;
        v = ok ? *(const short8*)(h16 + (size_t)n * H + q * 8) : z;
        *(short8*)(smA + ((size_t)0 * 256 + t) * 8) = v;
        v = ok ? *(const short8*)(h16 + (size_t)n * H + 32 + q * 8) : z;
        *(short8*)(smA + ((size_t)1 * 256 + t) * 8) = v;
#pragma unroll
        for (int kk = 0; kk < 2; ++kk) {
            short8 u = z;
            if (ok) {
                const float4 a = *(const float4*)(agg + (size_t)n * H + kk * 32 + q * 8);
                const float4 b = *(const float4*)(agg + (size_t)n * H + kk * 32 + q * 8 + 4);
                u[0] = bf16r(a.x); u[1] = bf16r(a.y); u[2] = bf16r(a.z); u[3] = bf16r(a.w);
                u[4] = bf16r(b.x); u[5] = bf16r(b.y); u[6] = bf16r(b.z); u[7] = bf16r(b.w);
            }
            *(short8*)(smA + ((size_t)(2 + kk) * 256 + t) * 8) = u;
        }
    }

    floatx4 acc[4] = {{0.f,0.f,0.f,0.f},{0.f,0.f,0.f,0.f},{0.f,0.f,0.f,0.f},{0.f,0.f,0.f,0.f}};
#pragma unroll
    for (int kt = 0; kt < 4; ++kt) {
        const short8 a = *(const short8*)(smA + ((size_t)(kt * 4 + w) * 64 + l) * 8);
#pragma unroll
        for (int nt = 0; nt < 4; ++nt) {
            const short8 b = *(const short8*)(W1f + ((size_t)(kt * 4 + nt) * 64 + l) * 8);
            acc[nt] = __builtin_amdgcn_mfma_f32_16x16x32_bf16(a, b, acc[nt], 0, 0, 0);
        }
    }
#pragma unroll
    for (int nt = 0; nt < 4; ++nt) {
        const float bb = b1[nt * 16 + m15];
#pragma unroll
        for (int r = 0; r < 4; ++r)
            smC[(w * 16 + q * 4 + r) * CSTR + nt * 16 + m15] = fmaxf(acc[nt][r] + bb, 0.f);
    }

#pragma unroll
    for (int kk = 0; kk < 2; ++kk) {
        const int k0 = kk * 32 + q * 8;
        short8 v;
#pragma unroll
        for (int j = 0; j < 8; ++j) v[j] = bf16r(smC[m * CSTR + k0 + j]);
        *(short8*)(smA + ((size_t)kk * 256 + t) * 8) = v;
    }

    floatx4 c2[4] = {{0.f,0.f,0.f,0.f},{0.f,0.f,0.f,0.f},{0.f,0.f,0.f,0.f},{0.f,0.f,0.f,0.f}};
#pragma unroll
    for (int kt = 0; kt < 2; ++kt) {
        const short8 a = *(const short8*)(smA + ((size_t)(kt * 4 + w) * 64 + l) * 8);
#pragma unroll
        for (int nt = 0; nt < 4; ++nt) {
            const short8 b = *(const short8*)(W2f + ((size_t)(kt * 4 + nt) * 64 + l) * 8);
            c2[nt] = __builtin_amdgcn_mfma_f32_16x16x32_bf16(a, b, c2[nt], 0, 0, 0);
        }
    }
#pragma unroll
    for (int nt = 0; nt < 4; ++nt) {
        const float bb = b2[nt * 16 + m15];
#pragma unroll
        for (int r = 0; r < 4; ++r)  // outer relu
            smC[(w * 16 + q * 4 + r) * CSTR + nt * 16 + m15] = fmaxf(c2[nt][r] + bb, 0.f);
    }

    // write bf16 h (always) + fp32 h (final layer only, hout != null)
#pragma unroll 1
    for (int r = 0; r < 16; ++r) {
        const int mm = w * 16 + r;
        const int n = n0 + mm;
        if (n >= N) continue;
        if (hout) hout[(size_t)n * H + l] = smC[mm * CSTR + l];
        if (l < 32) {
            const unsigned lo = (unsigned short)bf16r(smC[mm * CSTR + 2 * l]);
            const unsigned hi = (unsigned short)bf16r(smC[mm * CSTR + 2 * l + 1]);
            ((unsigned*)(h16out + (size_t)n * H))[l] = lo | (hi << 16);
        }
    }
}

// ---- pool over sorted batch_idx: per-wave run merge ----
__global__ void pool_kernel(const float* __restrict__ h,
                            const int* __restrict__ batch,
                            float* __restrict__ pooled,
                            float* __restrict__ counts, int N)
{
    const int t = blockIdx.x * blockDim.x + threadIdx.x;
    const int wave = t >> 6, l = t & 63;
    const int base = wave * 32;
    if (base >= N) return;
    const int end = (base + 32 < N) ? base + 32 : N;
    int cur = __builtin_amdgcn_readfirstlane(batch[base]);
    float run = h[(size_t)base * H + l];
    int c = 1;
#pragma unroll 1
    for (int n = base + 1; n < end; ++n) {
        const int b = __builtin_amdgcn_readfirstlane(batch[n]);
        const float v = h[(size_t)n * H + l];
        if (b != cur) {
            atomicAdd(&pooled[(size_t)cur * H + l], run);
            if (l == 0) atomicAdd(&counts[cur], (float)c);
            run = v; cur = b; c = 1;
        } else { run += v; ++c; }
    }
    atomicAdd(&pooled[(size_t)cur * H + l], run);
    if (l == 0) atomicAdd(&counts[cur], (float)c);
}

__global__ void head_kernel(const float* __restrict__ pooled,
                            const float* __restrict__ counts,
                            const float* __restrict__ lin1w,
                            const float* __restrict__ lin1b,
                            const float* __restrict__ lin2w,
                            const float* __restrict__ lin2b,
                            float* __restrict__ out, int G)
{
    int g = blockIdx.x;
    int j = threadIdx.x;
    __shared__ float p[H];
    float c = fmaxf(counts[g], 1.0f);
    p[j] = pooled[(size_t)g * H + j] / c;
    __syncthreads();

    float accj = lin1b[j];
#pragma unroll
    for (int k = 0; k < H; ++k) accj = fmaf(p[k], lin1w[k * H + j], accj);
    accj = fmaxf(accj, 0.0f) * lin2w[j];
#pragma unroll
    for (int off = 32; off >= 1; off >>= 1) accj += __shfl_down(accj, off);
    if (j == 0) out[g] = accj + lin2b[0];
}

extern "C" void kernel_launch(void* const* d_in, const int* in_sizes, int n_in,
                              void* d_out, int out_size, void* d_ws, size_t ws_size,
                              hipStream_t stream)
{
    const float* x      = (const float*)d_in[0];
    const int*   eidx   = (const int*)d_in[1];
    const float* ea     = (const float*)d_in[2];
    const int*   batch  = (const int*)d_in[3];
    const float* mW1    = (const float*)d_in[4];
    const float* mb1    = (const float*)d_in[5];
    const float* mW2    = (const float*)d_in[6];
    const float* mb2    = (const float*)d_in[7];
    const float* uW1    = (const float*)d_in[8];
    const float* ub1    = (const float*)d_in[9];
    const float* uW2    = (const float*)d_in[10];
    const float* ub2    = (const float*)d_in[11];
    const float* lin1w  = (const float*)d_in[12];
    const float* lin1b  = (const float*)d_in[13];
    const float* lin2w  = (const float*)d_in[14];
    const float* lin2b  = (const float*)d_in[15];

    const int N = in_sizes[0] / H;
    const int E = in_sizes[1] / 2;
    const int G = out_size;

    // ---- workspace layout (16B-aligned chunks) ----
    short* mW1f = (short*)d_ws;                  // 30720 shorts
    short* mW2f = mW1f + 30720;                  // 12288
    short* uW1f = mW2f + 12288;                  // 24576
    short* uW2f = uW1f + 24576;                  // 12288 -> 159744 B
    short* x16  = uW2f + 12288;
    short* h16A = x16  + (size_t)N * H;
    short* h16B = h16A + (size_t)N * H;
    short* ea16 = h16B + (size_t)N * H;          // E*16 shorts
    char*  pch  = (char*)(ea16 + (size_t)E * 16);
    int* cnt    = (int*)pch;          pch += (size_t)N * 4;
    int* offs   = (int*)pch;          pch += (size_t)N * 4;
    int* bsum   = (int*)pch;          pch += 256;
    int* eperm  = (int*)pch;          pch += (size_t)E * 4;
    int* src_s  = (int*)pch;          pch += (size_t)E * 4;
    int* dst_s  = (int*)pch;          pch += (size_t)E * 4;
    float* hF     = (float*)pch;
    float* agg    = hF  + (size_t)N * H;
    float* pooled = agg + (size_t)N * H;
    float* counts = pooled + (size_t)G * H;

    const int* esrc = eidx;
    const int* edst = eidx + E;

    // ---- weight packing + x -> bf16 ----
    prep_frag<<<(3*5*4*64 + 255) / 256, 256, 0, stream>>>(mW1, mW1f, 144, 5, 3*5*4*64);
    prep_frag<<<(3*2*4*64 + 255) / 256, 256, 0, stream>>>(mW2, mW2f,  64, 2, 3*2*4*64);
    prep_frag<<<(3*4*4*64 + 255) / 256, 256, 0, stream>>>(uW1, uW1f, 128, 4, 3*4*4*64);
    prep_frag<<<(3*2*4*64 + 255) / 256, 256, 0, stream>>>(uW2, uW2f,  64, 2, 3*2*4*64);
    to_bf16<<<((size_t)N * H / 8 + 255) / 256, 256, 0, stream>>>(x, x16, N * H / 8);

    // ---- dst-sort prep ----
    hipMemsetAsync(cnt, 0, (size_t)N * 4, stream);
    hist_kernel<<<(E + 255) / 256, 256, 0, stream>>>(edst, cnt, E);
    {
        const int nb = (N + 1023) / 1024;
        scan_block<<<nb, 1024, 0, stream>>>(cnt, offs, bsum, N);
        scan_bsum<<<1, 64, 0, stream>>>(bsum, nb);
        add_bsum<<<(N + 255) / 256, 256, 0, stream>>>(offs, bsum, N);
    }
    build_perm<<<(E + 255) / 256, 256, 0, stream>>>(edst, offs, eperm, E);
    gather_edges<<<(E + 255) / 256, 256, 0, stream>>>(eperm, esrc, edst, ea,
                                                      src_s, dst_s, ea16, E);

    const short* hin = x16;
    short* houts16[3] = {h16A, h16B, h16A};
    const int nEB = E / 128;
    const int nNB = (N + 63) / 64;

    for (int lyr = 0; lyr < 3; ++lyr) {
        hipMemsetAsync(agg, 0, (size_t)N * H * sizeof(float), stream);
        edge_msg_mfma<<<nEB, 512, SMEM_E, stream>>>(
            hin, src_s, dst_s, ea16,
            mW1f + (size_t)lyr * 10240, mb1 + (size_t)lyr * H,
            mW2f + (size_t)lyr * 4096,  mb2 + (size_t)lyr * H,
            agg);
        node_update_mfma<<<nNB, 256, SMEM_N, stream>>>(
            hin, agg,
            uW1f + (size_t)lyr * 8192, ub1 + (size_t)lyr * H,
            uW2f + (size_t)lyr * 4096, ub2 + (size_t)lyr * H,
            houts16[lyr], (lyr == 2) ? hF : (float*)nullptr, N);
        hin = houts16[lyr];
    }

    hipMemsetAsync(pooled, 0, ((size_t)G * H + G) * sizeof(float), stream);
    {
        const int waves = (N + 31) / 32;
        pool_kernel<<<(waves * 64 + 255) / 256, 256, 0, stream>>>(hF, batch, pooled, counts, N);
    }
    head_kernel<<<G, H, 0, stream>>>(pooled, counts, lin1w, lin1b, lin2w, lin2b,
                                     (float*)d_out, G);
}

// Round 6
// 460.224 us; speedup vs baseline: 18.9835x; 1.5417x over previous
//
#include <hip/hip_runtime.h>

#define H 64

typedef __attribute__((ext_vector_type(8))) short short8;
typedef __attribute__((ext_vector_type(4))) float floatx4;

__device__ __forceinline__ short bf16r(float f) {
    union { float f; unsigned u; } v; v.f = f;
    unsigned r = v.u + 0x7FFFu + ((v.u >> 16) & 1u);
    return (short)(r >> 16);
}

// ---------------- fused prep: weight B-frag packing + x->bf16 ----------------
// W[K][64] fp32 -> bf16 B-fragments [KT][4][64][8]: lane holds
// B[k = kt*32 + (lane>>4)*8 + j][n = nt*16 + (lane&15)]
__device__ __forceinline__ void pack_one(const float* W, short* out, int K, int KT, int tid)
{
    const int lane = tid & 63;
    const int nt = (tid >> 6) & 3;
    const int lk = tid >> 8;          // lay*KT + kt
    const int kt = lk % KT;
    const int lay = lk / KT;
    const int n = nt * 16 + (lane & 15);
    const int kbase = kt * 32 + ((lane >> 4) & 3) * 8;
    short8 v;
#pragma unroll
    for (int j = 0; j < 8; ++j) {
        const int k = kbase + j;
        const float w = (k < K) ? W[((size_t)lay * K + k) * H + n] : 0.f;
        v[j] = bf16r(w);
    }
    *(short8*)(out + (size_t)tid * 8) = v;
}

#define T_MW1 3840   // 3*5*4*64
#define T_MW2 1536   // 3*2*4*64
#define T_UW1 3072   // 3*4*4*64
#define T_UW2 1536

__global__ void prep_all(const float* __restrict__ mW1, const float* __restrict__ mW2,
                         const float* __restrict__ uW1, const float* __restrict__ uW2,
                         const float* __restrict__ x,
                         short* __restrict__ mW1f, short* __restrict__ mW2f,
                         short* __restrict__ uW1f, short* __restrict__ uW2f,
                         short* __restrict__ x16, int n8)
{
    int g = blockIdx.x * blockDim.x + threadIdx.x;
    if (g < T_MW1) { pack_one(mW1, mW1f, 144, 5, g); return; }
    g -= T_MW1;
    if (g < T_MW2) { pack_one(mW2, mW2f, 64, 2, g); return; }
    g -= T_MW2;
    if (g < T_UW1) { pack_one(uW1, uW1f, 128, 4, g); return; }
    g -= T_UW1;
    if (g < T_UW2) { pack_one(uW2, uW2f, 64, 2, g); return; }
    g -= T_UW2;
    if (g < n8) {
        const float4 a = ((const float4*)x)[2 * g];
        const float4 b = ((const float4*)x)[2 * g + 1];
        short8 v;
        v[0] = bf16r(a.x); v[1] = bf16r(a.y); v[2] = bf16r(a.z); v[3] = bf16r(a.w);
        v[4] = bf16r(b.x); v[5] = bf16r(b.y); v[6] = bf16r(b.z); v[7] = bf16r(b.w);
        ((short8*)x16)[g] = v;
    }
}

// ---------------- dst-sort prep ----------------
__global__ void hist_kernel(const int* __restrict__ edst, int* __restrict__ cnt, int E)
{
    int e = blockIdx.x * blockDim.x + threadIdx.x;
    if (e < E) atomicAdd(&cnt[edst[e]], 1);
}

__global__ void scan_block(const int* __restrict__ cnt, int* __restrict__ offs,
                           int* __restrict__ bsum, int n)
{
    __shared__ int buf[1024];
    const int t = threadIdx.x;
    const int gid = blockIdx.x * 1024 + t;
    const int v = (gid < n) ? cnt[gid] : 0;
    buf[t] = v;
    __syncthreads();
#pragma unroll
    for (int off = 1; off < 1024; off <<= 1) {
        int x = (t >= off) ? buf[t - off] : 0;
        __syncthreads();
        buf[t] += x;
        __syncthreads();
    }
    if (gid < n) offs[gid] = buf[t] - v;          // exclusive within block
    if (t == 1023) bsum[blockIdx.x] = buf[1023];
}

__global__ void scan_bsum(int* __restrict__ bsum, int nb)
{
    if (threadIdx.x == 0) {
        int acc = 0;
        for (int i = 0; i < nb; ++i) { int v = bsum[i]; bsum[i] = acc; acc += v; }
    }
}

__global__ void add_bsum(int* __restrict__ offs, const int* __restrict__ bsum, int n)
{
    int gid = blockIdx.x * blockDim.x + threadIdx.x;
    if (gid < n) offs[gid] += bsum[gid >> 10];
}

// build permutation AND gather src/dst/edge_attr(bf16) into sorted order in one pass
__global__ void build_perm_gather(const int* __restrict__ esrc, const int* __restrict__ edst,
                                  const float* __restrict__ ea, int* __restrict__ offs,
                                  int* __restrict__ src_s, int* __restrict__ dst_s,
                                  short* __restrict__ ea16, int E)
{
    int e = blockIdx.x * blockDim.x + threadIdx.x;
    if (e >= E) return;
    const int d = edst[e];
    const int p = atomicAdd(&offs[d], 1);
    src_s[p] = esrc[e];
    dst_s[p] = d;
    const float4* r = (const float4*)(ea + (size_t)e * 16);
    const float4 a = r[0], b = r[1], c = r[2], d4 = r[3];
    short8 v0, v1;
    v0[0] = bf16r(a.x); v0[1] = bf16r(a.y); v0[2] = bf16r(a.z); v0[3] = bf16r(a.w);
    v0[4] = bf16r(b.x); v0[5] = bf16r(b.y); v0[6] = bf16r(b.z); v0[7] = bf16r(b.w);
    v1[0] = bf16r(c.x); v1[1] = bf16r(c.y); v1[2] = bf16r(c.z); v1[3] = bf16r(c.w);
    v1[4] = bf16r(d4.x); v1[5] = bf16r(d4.y); v1[6] = bf16r(d4.z); v1[7] = bf16r(d4.w);
    short8* o = (short8*)(ea16 + (size_t)p * 16);
    o[0] = v0; o[1] = v1;
}

// ---------------- edge-message MLP: zero-LDS A-path, register run-merge scatter ----
// 256 thr = 4 waves, M-tile 64 (16 edges/wave). Wave-private LDS scratch 4224 B:
//   phase 1: C1 bf16 [16][72]  (2304 B) -- conflict-free writes, b128 reads ARE A2 frags
//   phase 2: C2 fp32 [16][66]  (4224 B) -- 2-way (free) b32 pattern
__global__ __launch_bounds__(256, 5)
void edge_msg_mfma(const short* __restrict__ h16,
                   const int* __restrict__ src_s,
                   const int* __restrict__ dst_s,
                   const short* __restrict__ ea16,
                   const short* __restrict__ W1f, const float* __restrict__ b1,
                   const short* __restrict__ W2f, const float* __restrict__ b2,
                   float* __restrict__ agg)
{
    __shared__ char smraw[16896];
    const int t = threadIdx.x;
    const int w = t >> 6, l = t & 63, q = l >> 4, m15 = l & 15;
    const int i = blockIdx.x * 64 + w * 16 + m15;
    const int d = dst_s[i];
    const int s = src_s[i];

    short* C1 = (short*)(smraw + w * 4224);
    float* C2 = (float*)(smraw + w * 4224);

    // ---- A-fragments straight from global (each IS one lane's 16B frag) ----
    const short8 a0 = *(const short8*)(h16 + (size_t)d * H + q * 8);
    const short8 a1 = *(const short8*)(h16 + (size_t)d * H + 32 + q * 8);
    const short8 a2 = *(const short8*)(h16 + (size_t)s * H + q * 8);
    const short8 a3 = *(const short8*)(h16 + (size_t)s * H + 32 + q * 8);
    short8 a4 = {0, 0, 0, 0, 0, 0, 0, 0};
    if (q < 2) a4 = *(const short8*)(ea16 + (size_t)i * 16 + q * 8);

    float b1v[4], b2v[4];
#pragma unroll
    for (int nt = 0; nt < 4; ++nt) { b1v[nt] = b1[nt * 16 + m15]; b2v[nt] = b2[nt * 16 + m15]; }

    // ---- GEMM1: K=160 (144 padded), 5 k-tiles x 4 n-tiles ----
    floatx4 acc[4] = {{0,0,0,0},{0,0,0,0},{0,0,0,0},{0,0,0,0}};
#pragma unroll
    for (int nt = 0; nt < 4; ++nt) {
        acc[nt] = __builtin_amdgcn_mfma_f32_16x16x32_bf16(a0, *(const short8*)(W1f + ((0*4+nt)*64 + l)*8), acc[nt], 0,0,0);
        acc[nt] = __builtin_amdgcn_mfma_f32_16x16x32_bf16(a1, *(const short8*)(W1f + ((1*4+nt)*64 + l)*8), acc[nt], 0,0,0);
        acc[nt] = __builtin_amdgcn_mfma_f32_16x16x32_bf16(a2, *(const short8*)(W1f + ((2*4+nt)*64 + l)*8), acc[nt], 0,0,0);
        acc[nt] = __builtin_amdgcn_mfma_f32_16x16x32_bf16(a3, *(const short8*)(W1f + ((3*4+nt)*64 + l)*8), acc[nt], 0,0,0);
        acc[nt] = __builtin_amdgcn_mfma_f32_16x16x32_bf16(a4, *(const short8*)(W1f + ((4*4+nt)*64 + l)*8), acc[nt], 0,0,0);
    }

    // ---- relu -> C1 bf16 (row-major stride 72 shorts) ----
#pragma unroll
    for (int nt = 0; nt < 4; ++nt)
#pragma unroll
        for (int r = 0; r < 4; ++r)
            C1[(q * 4 + r) * 72 + nt * 16 + m15] = bf16r(fmaxf(acc[nt][r] + b1v[nt], 0.f));

    // ---- A2 fragments = direct b128 reads of C1 ----
    const short8 p0 = *(const short8*)(C1 + m15 * 72 + q * 8);
    const short8 p1 = *(const short8*)(C1 + m15 * 72 + 32 + q * 8);

    // ---- GEMM2: K=64 ----
    floatx4 c2[4] = {{0,0,0,0},{0,0,0,0},{0,0,0,0},{0,0,0,0}};
#pragma unroll
    for (int nt = 0; nt < 4; ++nt) {
        c2[nt] = __builtin_amdgcn_mfma_f32_16x16x32_bf16(p0, *(const short8*)(W2f + ((0*4+nt)*64 + l)*8), c2[nt], 0,0,0);
        c2[nt] = __builtin_amdgcn_mfma_f32_16x16x32_bf16(p1, *(const short8*)(W2f + ((1*4+nt)*64 + l)*8), c2[nt], 0,0,0);
    }

    // ---- C2 fp32 (+bias) into wave scratch; all lanes read C1 above before this (lockstep) ----
#pragma unroll
    for (int nt = 0; nt < 4; ++nt)
#pragma unroll
        for (int r = 0; r < 4; ++r)
            C2[(q * 4 + r) * 66 + nt * 16 + m15] = c2[nt][r] + b2v[nt];

    // ---- register run-merge scatter: dst ids to SGPRs, rows to VGPRs, unrolled ----
    int dm[16];
#pragma unroll
    for (int mm = 0; mm < 16; ++mm)
        dm[mm] = __builtin_amdgcn_readlane(d, mm);   // lane mm holds row mm's dst
    float v[16];
#pragma unroll
    for (int mm = 0; mm < 16; ++mm) v[mm] = C2[mm * 66 + l];

    float run = v[0];
    int cur = dm[0];
#pragma unroll
    for (int mm = 1; mm < 16; ++mm) {
        if (dm[mm] != cur) {
            atomicAdd(&agg[(size_t)cur * H + l], run);
            run = v[mm]; cur = dm[mm];
        } else {
            run += v[mm];
        }
    }
    atomicAdd(&agg[(size_t)cur * H + l], run);
}

// ---------------- node-update MLP: zero-LDS A-path ----------------
// non-final: bf16 h stores straight from registers (no LDS C2, no extraction)
// final: fused mean-pool -- register run-merge over sorted batch_idx into pooled/counts
__global__ __launch_bounds__(256, 5)
void node_update_mfma(const short* __restrict__ h16,
                      const float* __restrict__ agg,
                      const short* __restrict__ W1f, const float* __restrict__ b1,
                      const short* __restrict__ W2f, const float* __restrict__ b2,
                      short* __restrict__ h16out,        // non-final
                      const int* __restrict__ batch,     // final
                      float* __restrict__ pooled, float* __restrict__ counts,
                      int N)
{
    __shared__ char smraw[16896];
    const int t = threadIdx.x;
    const int w = t >> 6, l = t & 63, q = l >> 4, m15 = l & 15;
    const int n0 = blockIdx.x * 64;
    const int n = n0 + w * 16 + m15;
    const bool ok = n < N;

    short* C1 = (short*)(smraw + w * 4224);
    float* C2 = (float*)(smraw + w * 4224);

    short8 a0 = {0,0,0,0,0,0,0,0}, a1 = a0, a2 = a0, a3 = a0;
    if (ok) {
        a0 = *(const short8*)(h16 + (size_t)n * H + q * 8);
        a1 = *(const short8*)(h16 + (size_t)n * H + 32 + q * 8);
        const float4 f0 = *(const float4*)(agg + (size_t)n * H + q * 8);
        const float4 f1 = *(const float4*)(agg + (size_t)n * H + q * 8 + 4);
        const float4 f2 = *(const float4*)(agg + (size_t)n * H + 32 + q * 8);
        const float4 f3 = *(const float4*)(agg + (size_t)n * H + 32 + q * 8 + 4);
        a2[0] = bf16r(f0.x); a2[1] = bf16r(f0.y); a2[2] = bf16r(f0.z); a2[3] = bf16r(f0.w);
        a2[4] = bf16r(f1.x); a2[5] = bf16r(f1.y); a2[6] = bf16r(f1.z); a2[7] = bf16r(f1.w);
        a3[0] = bf16r(f2.x); a3[1] = bf16r(f2.y); a3[2] = bf16r(f2.z); a3[3] = bf16r(f2.w);
        a3[4] = bf16r(f3.x); a3[5] = bf16r(f3.y); a3[6] = bf16r(f3.z); a3[7] = bf16r(f3.w);
    }

    float b1v[4], b2v[4];
#pragma unroll
    for (int nt = 0; nt < 4; ++nt) { b1v[nt] = b1[nt * 16 + m15]; b2v[nt] = b2[nt * 16 + m15]; }

    floatx4 acc[4] = {{0,0,0,0},{0,0,0,0},{0,0,0,0},{0,0,0,0}};
#pragma unroll
    for (int nt = 0; nt < 4; ++nt) {
        acc[nt] = __builtin_amdgcn_mfma_f32_16x16x32_bf16(a0, *(const short8*)(W1f + ((0*4+nt)*64 + l)*8), acc[nt], 0,0,0);
        acc[nt] = __builtin_amdgcn_mfma_f32_16x16x32_bf16(a1, *(const short8*)(W1f + ((1*4+nt)*64 + l)*8), acc[nt], 0,0,0);
        acc[nt] = __builtin_amdgcn_mfma_f32_16x16x32_bf16(a2, *(const short8*)(W1f + ((2*4+nt)*64 + l)*8), acc[nt], 0,0,0);
        acc[nt] = __builtin_amdgcn_mfma_f32_16x16x32_bf16(a3, *(const short8*)(W1f + ((3*4+nt)*64 + l)*8), acc[nt], 0,0,0);
    }

#pragma unroll
    for (int nt = 0; nt < 4; ++nt)
#pragma unroll
        for (int r = 0; r < 4; ++r)
            C1[(q * 4 + r) * 72 + nt * 16 + m15] = bf16r(fmaxf(acc[nt][r] + b1v[nt], 0.f));

    const short8 p0 = *(const short8*)(C1 + m15 * 72 + q * 8);
    const short8 p1 = *(const short8*)(C1 + m15 * 72 + 32 + q * 8);

    floatx4 c2[4] = {{0,0,0,0},{0,0,0,0},{0,0,0,0},{0,0,0,0}};
#pragma unroll
    for (int nt = 0; nt < 4; ++nt) {
        c2[nt] = __builtin_amdgcn_mfma_f32_16x16x32_bf16(p0, *(const short8*)(W2f + ((0*4+nt)*64 + l)*8), c2[nt], 0,0,0);
        c2[nt] = __builtin_amdgcn_mfma_f32_16x16x32_bf16(p1, *(const short8*)(W2f + ((1*4+nt)*64 + l)*8), c2[nt], 0,0,0);
    }

    if (!batch) {
        // non-final: outer relu, bf16 stores straight from registers
#pragma unroll
        for (int nt = 0; nt < 4; ++nt)
#pragma unroll
            for (int r = 0; r < 4; ++r) {
                const int nn = n0 + w * 16 + q * 4 + r;
                if (nn < N)
                    h16out[(size_t)nn * H + nt * 16 + m15] =
                        bf16r(fmaxf(c2[nt][r] + b2v[nt], 0.f));
            }
        return;
    }

    // final layer: outer relu -> C2 -> register run-merge mean-pool
#pragma unroll
    for (int nt = 0; nt < 4; ++nt)
#pragma unroll
        for (int r = 0; r < 4; ++r)
            C2[(q * 4 + r) * 66 + nt * 16 + m15] = fmaxf(c2[nt][r] + b2v[nt], 0.f);

    const int bi = ok ? batch[n] : -1;
    int bm[16];
#pragma unroll
    for (int mm = 0; mm < 16; ++mm)
        bm[mm] = __builtin_amdgcn_readlane(bi, mm);
    float v[16];
#pragma unroll
    for (int mm = 0; mm < 16; ++mm) v[mm] = C2[mm * 66 + l];

    float run = v[0];
    int cur = bm[0];
    int len = 1;
#pragma unroll
    for (int mm = 1; mm < 16; ++mm) {
        if (bm[mm] != cur) {
            if (cur >= 0) {
                atomicAdd(&pooled[(size_t)cur * H + l], run);
                if (l == 0) atomicAdd(&counts[cur], (float)len);
            }
            run = v[mm]; cur = bm[mm]; len = 1;
        } else {
            run += v[mm]; ++len;
        }
    }
    if (cur >= 0) {
        atomicAdd(&pooled[(size_t)cur * H + l], run);
        if (l == 0) atomicAdd(&counts[cur], (float)len);
    }
}

// ---------------- head ----------------
__global__ void head_kernel(const float* __restrict__ pooled,
                            const float* __restrict__ counts,
                            const float* __restrict__ lin1w,
                            const float* __restrict__ lin1b,
                            const float* __restrict__ lin2w,
                            const float* __restrict__ lin2b,
                            float* __restrict__ out, int G)
{
    int g = blockIdx.x;
    int j = threadIdx.x;
    __shared__ float p[H];
    float c = fmaxf(counts[g], 1.0f);
    p[j] = pooled[(size_t)g * H + j] / c;
    __syncthreads();

    float accj = lin1b[j];
#pragma unroll
    for (int k = 0; k < H; ++k) accj = fmaf(p[k], lin1w[k * H + j], accj);
    accj = fmaxf(accj, 0.0f) * lin2w[j];
#pragma unroll
    for (int off = 32; off >= 1; off >>= 1) accj += __shfl_down(accj, off);
    if (j == 0) out[g] = accj + lin2b[0];
}

extern "C" void kernel_launch(void* const* d_in, const int* in_sizes, int n_in,
                              void* d_out, int out_size, void* d_ws, size_t ws_size,
                              hipStream_t stream)
{
    const float* x      = (const float*)d_in[0];
    const int*   eidx   = (const int*)d_in[1];
    const float* ea     = (const float*)d_in[2];
    const int*   batch  = (const int*)d_in[3];
    const float* mW1    = (const float*)d_in[4];
    const float* mb1    = (const float*)d_in[5];
    const float* mW2    = (const float*)d_in[6];
    const float* mb2    = (const float*)d_in[7];
    const float* uW1    = (const float*)d_in[8];
    const float* ub1    = (const float*)d_in[9];
    const float* uW2    = (const float*)d_in[10];
    const float* ub2    = (const float*)d_in[11];
    const float* lin1w  = (const float*)d_in[12];
    const float* lin1b  = (const float*)d_in[13];
    const float* lin2w  = (const float*)d_in[14];
    const float* lin2b  = (const float*)d_in[15];

    const int N = in_sizes[0] / H;
    const int E = in_sizes[1] / 2;
    const int G = out_size;

    // ---- workspace ----
    short* mW1f = (short*)d_ws;                  // 30720 shorts
    short* mW2f = mW1f + 30720;                  // 12288
    short* uW1f = mW2f + 12288;                  // 24576
    short* uW2f = uW1f + 24576;                  // 12288 -> 159744 B
    short* x16  = uW2f + 12288;                  // N*H
    short* h16A = x16  + (size_t)N * H;
    short* h16B = h16A + (size_t)N * H;
    short* ea16 = h16B + (size_t)N * H;          // E*16
    char*  pch  = (char*)(ea16 + (size_t)E * 16);
    int* offs   = (int*)pch;          pch += (size_t)N * 4;
    int* bsum   = (int*)pch;          pch += 256;
    int* src_s  = (int*)pch;          pch += (size_t)E * 4;
    int* dst_s  = (int*)pch;          pch += (size_t)E * 4;
    // contiguous zero region: [cnt N ints][agg3 3*N*H][pooled G*H][counts G]
    int*   cnt    = (int*)pch;
    float* agg3   = (float*)(pch + (size_t)N * 4);
    float* pooled = agg3 + (size_t)3 * N * H;
    float* counts = pooled + (size_t)G * H;
    const size_t zero_bytes = (size_t)N * 4 + ((size_t)3 * N * H + (size_t)G * H + G) * 4;

    const int* esrc = eidx;
    const int* edst = eidx + E;

    // ---- prep: weights + x16 (1 kernel) ----
    {
        const int n8 = N * H / 8;
        const int total = T_MW1 + T_MW2 + T_UW1 + T_UW2 + n8;
        prep_all<<<(total + 255) / 256, 256, 0, stream>>>(
            mW1, mW2, uW1, uW2, x, mW1f, mW2f, uW1f, uW2f, x16, n8);
    }

    hipMemsetAsync(cnt, 0, zero_bytes, stream);

    // ---- dst-sort prep ----
    hist_kernel<<<(E + 255) / 256, 256, 0, stream>>>(edst, cnt, E);
    {
        const int nb = (N + 1023) / 1024;
        scan_block<<<nb, 1024, 0, stream>>>(cnt, offs, bsum, N);
        scan_bsum<<<1, 64, 0, stream>>>(bsum, nb);
        add_bsum<<<(N + 255) / 256, 256, 0, stream>>>(offs, bsum, N);
    }
    build_perm_gather<<<(E + 255) / 256, 256, 0, stream>>>(
        esrc, edst, ea, offs, src_s, dst_s, ea16, E);

    const short* hin = x16;
    short* houts16[3] = {h16A, h16B, nullptr};
    const int nEB = E / 64;                      // 12500 exact
    const int nNB = (N + 63) / 64;

    for (int lyr = 0; lyr < 3; ++lyr) {
        float* agg = agg3 + (size_t)lyr * N * H;
        edge_msg_mfma<<<nEB, 256, 0, stream>>>(
            hin, src_s, dst_s, ea16,
            mW1f + (size_t)lyr * 10240, mb1 + (size_t)lyr * H,
            mW2f + (size_t)lyr * 4096,  mb2 + (size_t)lyr * H,
            agg);
        node_update_mfma<<<nNB, 256, 0, stream>>>(
            hin, agg,
            uW1f + (size_t)lyr * 8192, ub1 + (size_t)lyr * H,
            uW2f + (size_t)lyr * 4096, ub2 + (size_t)lyr * H,
            houts16[lyr],
            (lyr == 2) ? batch : (const int*)nullptr,
            pooled, counts, N);
        hin = houts16[lyr];
    }

    head_kernel<<<G, H, 0, stream>>>(pooled, counts, lin1w, lin1b, lin2w, lin2b,
                                     (float*)d_out, G);
}